// Round 10
// baseline (3123.218 us; speedup 1.0000x reference)
//
#include <hip/hip_runtime.h>
#include <hip/hip_bf16.h>
#include <math.h>

// Problem constants
#define NPGc  10000
#define EPGc  32000
#define MLc   128
#define NNc   40000      // N
#define NEc   128000     // E
#define E2c   16000      // EPG/2
#define ZETAc 1e-6f
#define INVPc 0.53995680345572354f   // 1/1.852
#define PEXPc 1.852f
#define NSB   ((NNc + 255) / 256)    // 157 scan blocks

typedef __attribute__((ext_vector_type(8))) short short8;    // 8 bf16 (4 VGPRs)
typedef __attribute__((ext_vector_type(16))) float f32x16;   // 32x32 MFMA acc

// fast selu: __expf -> v_exp_f32
__device__ __forceinline__ float selu_f(float x) {
    float e = __expf(x) - 1.0f;
    return 1.0507009873554805f * (x > 0.0f ? x : 1.6732632423543772f * e);
}
// cheap split fp32 -> (hi, lo): hi = truncated top-16 bits (exact rem), lo = RNE(rem).
// product error ~2^-17 relative: far below the bf16-grade threshold.
__device__ __forceinline__ void splitt(float v, unsigned& hi, unsigned& lo) {
    unsigned u = __float_as_uint(v);
    hi = u >> 16;
    float rem = v - __uint_as_float(u & 0xffff0000u);
    __hip_bfloat16 l = __float2bfloat16(rem);
    lo = (unsigned short)*reinterpret_cast<short*>(&l);
}
__device__ __forceinline__ float signf(float x) {
    return (x > 0.0f) ? 1.0f : (x < 0.0f ? -1.0f : 0.0f);
}

// async global->LDS: 64 lanes x 4B, wave-uniform LDS base + lane*4
__device__ __forceinline__ void load_lds4(const unsigned* src, short* dst) {
    __builtin_amdgcn_global_load_lds(
        (const __attribute__((address_space(1))) unsigned*)src,
        (__attribute__((address_space(3))) unsigned*)dst, 4, 0, 0);
}

// ---------------- weight convert+split into 32x32-MFMA B-FRAGMENT-LINEAR layout -------
// B-frag for mfma_32x32x16: n = ct*32 + (lane&31), k = kc*16 + (lane>>5)*8 + j.
// dst[(((ct*nkc)+kc)*64 + lane)*8 + j]; wave B-load = base + lane*16B (contiguous 1KB).
__global__ void k_wconv_frag(const float* __restrict__ src, short* __restrict__ dh,
                             short* __restrict__ dl, int nkc /* = K/16 */) {
    int gid = blockIdx.x * 256 + threadIdx.x;   // one thread per (frag, lane)
    int total = 4 * nkc * 64;                   // ct(4) x kc(nkc) x lane(64)
    if (gid >= total) return;
    int lane = gid & 63;
    int frag = gid >> 6;
    int kc = frag % nkc;
    int ct = frag / nkc;
    int col = ct * 32 + (lane & 31);
    int kbase = kc * 16 + (lane >> 5) * 8;
    size_t o = (size_t)gid * 8;
#pragma unroll
    for (int j = 0; j < 8; j++) {
        unsigned h, l;
        splitt(src[(size_t)(kbase + j) * 128 + col], h, l);
        dh[o + j] = (short)h;
        dl[o + j] = (short)l;
    }
}

// ---------------- CSR build (by rcvr) ----------------
__global__ void k_zero_i(int* p, int n) {
    int i = blockIdx.x * 256 + threadIdx.x;
    if (i < n) p[i] = 0;
}
__global__ void k_count(const int* __restrict__ rcvr, int* __restrict__ deg) {
    int e = blockIdx.x * 256 + threadIdx.x;
    if (e < NEc) atomicAdd(&deg[rcvr[e]], 1);
}
// 3-phase multi-block exclusive scan
__global__ void k_scan1(const int* __restrict__ deg, int* __restrict__ partial) {
    __shared__ int buf[256];
    int t = threadIdx.x;
    int i = blockIdx.x * 256 + t;
    buf[t] = (i < NNc) ? deg[i] : 0;
    __syncthreads();
    for (int off = 128; off > 0; off >>= 1) {
        if (t < off) buf[t] += buf[t + off];
        __syncthreads();
    }
    if (t == 0) partial[blockIdx.x] = buf[0];
}
__global__ void k_scan2(int* __restrict__ partial) {
    __shared__ int buf[256];
    int t = threadIdx.x;
    int v = (t < NSB) ? partial[t] : 0;
    buf[t] = v;
    __syncthreads();
    for (int off = 1; off < 256; off <<= 1) {
        int u = (t >= off) ? buf[t - off] : 0;
        __syncthreads();
        buf[t] += u;
        __syncthreads();
    }
    if (t < NSB) partial[t] = buf[t] - v;   // exclusive
}
__global__ void k_scan3(const int* __restrict__ deg, const int* __restrict__ partial,
                        int* __restrict__ rowstart, int* __restrict__ cursor) {
    __shared__ int buf[256];
    int t = threadIdx.x;
    int i = blockIdx.x * 256 + t;
    int v = (i < NNc) ? deg[i] : 0;
    buf[t] = v;
    __syncthreads();
    for (int off = 1; off < 256; off <<= 1) {
        int u = (t >= off) ? buf[t - off] : 0;
        __syncthreads();
        buf[t] += u;
        __syncthreads();
    }
    int excl = partial[blockIdx.x] + buf[t] - v;
    if (i < NNc) { rowstart[i] = excl; cursor[i] = excl; }
    if (i == NNc - 1) rowstart[NNc] = excl + v;
}
__global__ void k_scatter(const int* __restrict__ sndr, const int* __restrict__ rcvr,
                          int* __restrict__ cursor, int2* __restrict__ csr_se) {
    int e = blockIdx.x * 256 + threadIdx.x;
    if (e >= NEc) return;
    int rv = rcvr[e];
    int p = atomicAdd(&cursor[rv], 1);
    csr_se[p] = make_int2(sndr[e], e);
}

// ---------------- flows / elementwise ----------------
__global__ void k_qinit(const float* __restrict__ x, const float* __restrict__ r,
                        const int* __restrict__ sndr, const int* __restrict__ rcvr,
                        float* __restrict__ qh, float* __restrict__ qt) {
    int e = blockIdx.x * 256 + threadIdx.x;
    if (e >= NEc) return;
    float hv = x[2 * sndr[e]] - x[2 * rcvr[e]];
    float q = signf(hv) * __powf((fabsf(hv) + ZETAc) / (r[e] + ZETAc), INVPc);
    qh[e] = q; qt[e] = q;
}
__global__ void k_flows_q(const float* __restrict__ h, const float* __restrict__ r,
                          const int* __restrict__ sndr, const int* __restrict__ rcvr,
                          float* __restrict__ qt) {
    int e = blockIdx.x * 256 + threadIdx.x;
    if (e >= NEc) return;
    float hv = h[sndr[e]] - h[rcvr[e]];
    qt[e] = signf(hv) * __powf((fabsf(hv) + ZETAc) / (r[e] + ZETAc), INVPc);
}

// node-in, fused segsum: one WAVE per node. Produces split-selu g planes.
__global__ __launch_bounds__(256) void k_node_in_f(
    const float* __restrict__ qh, const int* __restrict__ rowstart,
    const int2* __restrict__ csr_se, const float* __restrict__ x,
    const float* __restrict__ W /*2x128*/,
    unsigned* __restrict__ gh_u, unsigned* __restrict__ gl_u) {
    const int tid = threadIdx.x;
    const int lane = tid & 63;
    const int n = blockIdx.x * 4 + (tid >> 6);
    if (n >= NNc) return;
    int p0 = rowstart[n], p1 = rowstart[n + 1];
    float s = 0.0f;
    for (int p = p0 + lane; p < p1; p += 64) s += qh[csr_se[p].y];
#pragma unroll
    for (int off = 1; off < 64; off <<= 1) s += __shfl_xor(s, off, 64);
    float s0 = selu_f(s);
    float s1 = selu_f(x[2 * n + 1]);
    int c = lane * 2;
    float g0 = s0 * W[c]     + s1 * W[MLc + c];
    float g1 = s0 * W[c + 1] + s1 * W[MLc + c + 1];
    unsigned h0, l0, h1, l1;
    splitt(selu_f(g0), h0, l0);
    splitt(selu_f(g1), h1, l1);
    gh_u[(size_t)n * 64 + lane] = h0 | (h1 << 16);
    gl_u[(size_t)n * 64 + lane] = l0 | (l1 << 16);
}

// one head-propagation iteration, CSR gather; hin has stride (2 for x, 1 for h buf)
__global__ __launch_bounds__(64) void k_head_iter(
    const float* __restrict__ x, const float* __restrict__ hin, int hstride,
    const float* __restrict__ hl, const int* __restrict__ rowstart,
    const int2* __restrict__ csr_se, float* __restrict__ hout) {
    int n = blockIdx.x * 64 + threadIdx.x;
    if (n >= NNc) return;
    float hv = hin[(size_t)n * hstride];
    float m = -3.0e38f;
    int p0 = rowstart[n], p1 = rowstart[n + 1];
    for (int p = p0; p < p1; p++) {
        int2 se = csr_se[p];
        m = fmaxf(m, hin[(size_t)se.x * hstride] - hl[se.y]);
    }
    float a = (m > -1e30f) ? m : hv;
    float hstar = x[2 * n];
    hout[n] = (hstar != 0.0f) ? hstar : fmaxf(hv, a);
}

// ---------------- split-bf16 32x32-MFMA MLP kernels ----------------
// 32-row tile, 256 threads = 4 waves; wave ct owns the 32-col tile [ct*32, ct*32+32).
// A-frag: row=lane&31, k=(lane>>5)*8+j (one ds_read_b128 per plane per kc).
// C/D: col=lane&31, row=(reg&3)+8*(reg>>2)+4*(lane>>5)  [m74/m101-verified].
// Emulated fp32: Ah*Bh + Al*Bh + Ah*Bl, fp32 acc.

#define MS_E 392   // 384+8 shorts
#define MS_N 264   // 256+8
#define TS   136   // 128+8

__global__ __launch_bounds__(256) void k_edge_mlp_mfma(
    const unsigned* __restrict__ gh_u, const unsigned* __restrict__ gl_u,
    const unsigned* __restrict__ zh_u, const unsigned* __restrict__ zl_u,
    short* __restrict__ zoh_s, short* __restrict__ zol_s,
    const short* __restrict__ W1h, const short* __restrict__ W1l,
    const short* __restrict__ W2h, const short* __restrict__ W2l,
    const int* __restrict__ sndr, const int* __restrict__ rcvr,
    const float* __restrict__ qt, const float* __restrict__ qh,
    const float* __restrict__ Wei, int zmode) {
    __shared__ short smem[2 * 32 * MS_E];        // 50176 B
    short* m_hi = smem;
    short* m_lo = smem + 32 * MS_E;
    short* t_hi = smem;                          // alias front (post-barrier)
    short* t_lo = smem + 32 * TS;
    const int tid = threadIdx.x;
    const int bi = blockIdx.x;
    const int x7 = bi & 7, jj = bi >> 3;
    const int e0 = ((x7 >> 1) * 1000 + (x7 & 1) * 500 + jj) * 32;   // XCD swizzle
    const int lane = tid & 63, wave = tid >> 6;  // 4 waves

    if (zmode == 0) {
        for (int t = wave; t < 96; t += 4) {
            int row = t & 31, region = t >> 5;
            int e = e0 + row;
            size_t o;
            const unsigned *ph, *pl;
            if (region == 0)      { o = (size_t)sndr[e] * 64; ph = gh_u; pl = gl_u; }
            else if (region == 1) { o = (size_t)rcvr[e] * 64; ph = gh_u; pl = gl_u; }
            else                  { o = (size_t)e * 64;       ph = zh_u; pl = zl_u; }
            load_lds4(ph + o + lane, &m_hi[row * MS_E + region * 128]);
            load_lds4(pl + o + lane, &m_lo[row * MS_E + region * 128]);
        }
    } else {
        for (int t = wave; t < 64; t += 4) {
            int row = t & 31, region = t >> 5;
            int e = e0 + row;
            size_t o = (region == 0) ? (size_t)sndr[e] * 64 : (size_t)rcvr[e] * 64;
            load_lds4(gh_u + o + lane, &m_hi[row * MS_E + region * 128]);
            load_lds4(gl_u + o + lane, &m_lo[row * MS_E + region * 128]);
        }
        for (int idx = tid; idx < 32 * 64; idx += 256) {
            int row = idx >> 6, cp = idx & 63;
            int e = e0 + row;
            float sqt = selu_f(qt[e]), sqh = selu_f(qh[e]);
            int c = 2 * cp;
            float z0 = sqt * Wei[c]     + sqh * Wei[MLc + c];
            float z1 = sqt * Wei[c + 1] + sqh * Wei[MLc + c + 1];
            unsigned h0, l0, h1, l1;
            splitt(selu_f(z0), h0, l0);
            splitt(selu_f(z1), h1, l1);
            int k = 256 + 2 * cp;
            *(unsigned*)&m_hi[row * MS_E + k] = h0 | (h1 << 16);
            *(unsigned*)&m_lo[row * MS_E + k] = l0 | (l1 << 16);
        }
    }
    __syncthreads();

    const int ct = wave;
    const int l31 = lane & 31, kh = lane >> 5;
    const int col = ct * 32 + l31;

    f32x16 acc;
#pragma unroll
    for (int i = 0; i < 16; i++) acc[i] = 0.0f;
#pragma unroll 4
    for (int kc = 0; kc < 24; kc++) {
        size_t wo = ((size_t)(ct * 24 + kc) * 64 + lane) * 8;   // fragment-linear
        short8 bh = *(const short8*)&W1h[wo];
        short8 bl = *(const short8*)&W1l[wo];
        const short* ap = &m_hi[l31 * MS_E + kc * 16 + kh * 8];
        short8 ah = *(const short8*)ap;
        short8 al = *(const short8*)(ap + 32 * MS_E);
        acc = __builtin_amdgcn_mfma_f32_32x32x16_bf16(ah, bh, acc, 0, 0, 0);
        acc = __builtin_amdgcn_mfma_f32_32x32x16_bf16(al, bh, acc, 0, 0, 0);
        acc = __builtin_amdgcn_mfma_f32_32x32x16_bf16(ah, bl, acc, 0, 0, 0);
    }
    __syncthreads();
#pragma unroll
    for (int reg = 0; reg < 16; reg++) {
        int row = (reg & 3) + 8 * (reg >> 2) + 4 * kh;
        unsigned h, l;
        splitt(selu_f(acc[reg]), h, l);
        t_hi[row * TS + col] = (short)h;
        t_lo[row * TS + col] = (short)l;
    }
    __syncthreads();

    f32x16 acc2;
#pragma unroll
    for (int i = 0; i < 16; i++) acc2[i] = 0.0f;
#pragma unroll
    for (int kc = 0; kc < 8; kc++) {
        size_t wo = ((size_t)(ct * 8 + kc) * 64 + lane) * 8;
        short8 bh = *(const short8*)&W2h[wo];
        short8 bl = *(const short8*)&W2l[wo];
        const short* ap = &t_hi[l31 * TS + kc * 16 + kh * 8];
        short8 ah = *(const short8*)ap;
        short8 al = *(const short8*)(ap + 32 * TS);
        acc2 = __builtin_amdgcn_mfma_f32_32x32x16_bf16(ah, bh, acc2, 0, 0, 0);
        acc2 = __builtin_amdgcn_mfma_f32_32x32x16_bf16(al, bh, acc2, 0, 0, 0);
        acc2 = __builtin_amdgcn_mfma_f32_32x32x16_bf16(ah, bl, acc2, 0, 0, 0);
    }
#pragma unroll
    for (int reg = 0; reg < 16; reg++) {
        int row = (reg & 3) + 8 * (reg >> 2) + 4 * kh;
        unsigned h, l;
        splitt(selu_f(acc2[reg]), h, l);
        size_t o = (size_t)(e0 + row) * 128 + col;
        zoh_s[o] = (short)h;
        zol_s[o] = (short)l;
    }
}

// node MLP: g-gather via global_load_lds + selu-space segment max of z planes
__global__ __launch_bounds__(256) void k_node_mlp_mfma(
    const unsigned* __restrict__ gh_u, const unsigned* __restrict__ gl_u,
    short* __restrict__ goh_s, short* __restrict__ gol_s,
    const unsigned* __restrict__ zh_u, const unsigned* __restrict__ zl_u,
    const int* __restrict__ rowstart, const int2* __restrict__ csr_se,
    const short* __restrict__ W1h, const short* __restrict__ W1l,
    const short* __restrict__ W2h, const short* __restrict__ W2l) {
    __shared__ short smem[2 * 32 * MS_N];        // 33792 B
    short* m_hi = smem;
    short* m_lo = smem + 32 * MS_N;
    short* t_hi = smem;
    short* t_lo = smem + 32 * TS;
    const int tid = threadIdx.x;
    const int n0 = blockIdx.x * 32;
    const int lane = tid & 63, wave = tid >> 6;

    for (int t = wave; t < 32; t += 4) {
        int n = n0 + t;
        load_lds4(gh_u + (size_t)n * 64 + lane, &m_hi[t * MS_N]);
        load_lds4(gl_u + (size_t)n * 64 + lane, &m_lo[t * MS_N]);
    }
    for (int idx = tid; idx < 32 * 64; idx += 256) {
        int row = idx >> 6, cp = idx & 63;
        int n = n0 + row;
        int p0 = rowstart[n], p1 = rowstart[n + 1];
        float b0 = -3.0e38f, b1 = -3.0e38f;
        unsigned bh0 = 0, bl0 = 0, bh1 = 0, bl1 = 0;  // default split(0)
        for (int p = p0; p < p1; p++) {
            size_t o = (size_t)csr_se[p].y * 64 + cp;
            unsigned vh = zh_u[o], vl = zl_u[o];
            float f0 = __uint_as_float(vh << 16) + __uint_as_float(vl << 16);
            float f1 = __uint_as_float(vh & 0xffff0000u) + __uint_as_float(vl & 0xffff0000u);
            if (f0 > b0) { b0 = f0; bh0 = vh & 0xffffu; bl0 = vl & 0xffffu; }
            if (f1 > b1) { b1 = f1; bh1 = vh & 0xffff0000u; bl1 = vl & 0xffff0000u; }
        }
        int k = 128 + 2 * cp;
        *(unsigned*)&m_hi[row * MS_N + k] = bh0 | bh1;
        *(unsigned*)&m_lo[row * MS_N + k] = bl0 | bl1;
    }
    __syncthreads();

    const int ct = wave;
    const int l31 = lane & 31, kh = lane >> 5;
    const int col = ct * 32 + l31;

    f32x16 acc;
#pragma unroll
    for (int i = 0; i < 16; i++) acc[i] = 0.0f;
#pragma unroll 4
    for (int kc = 0; kc < 16; kc++) {
        size_t wo = ((size_t)(ct * 16 + kc) * 64 + lane) * 8;
        short8 bh = *(const short8*)&W1h[wo];
        short8 bl = *(const short8*)&W1l[wo];
        const short* ap = &m_hi[l31 * MS_N + kc * 16 + kh * 8];
        short8 ah = *(const short8*)ap;
        short8 al = *(const short8*)(ap + 32 * MS_N);
        acc = __builtin_amdgcn_mfma_f32_32x32x16_bf16(ah, bh, acc, 0, 0, 0);
        acc = __builtin_amdgcn_mfma_f32_32x32x16_bf16(al, bh, acc, 0, 0, 0);
        acc = __builtin_amdgcn_mfma_f32_32x32x16_bf16(ah, bl, acc, 0, 0, 0);
    }
    __syncthreads();
#pragma unroll
    for (int reg = 0; reg < 16; reg++) {
        int row = (reg & 3) + 8 * (reg >> 2) + 4 * kh;
        unsigned h, l;
        splitt(selu_f(acc[reg]), h, l);
        t_hi[row * TS + col] = (short)h;
        t_lo[row * TS + col] = (short)l;
    }
    __syncthreads();

    f32x16 acc2;
#pragma unroll
    for (int i = 0; i < 16; i++) acc2[i] = 0.0f;
#pragma unroll
    for (int kc = 0; kc < 8; kc++) {
        size_t wo = ((size_t)(ct * 8 + kc) * 64 + lane) * 8;
        short8 bh = *(const short8*)&W2h[wo];
        short8 bl = *(const short8*)&W2l[wo];
        const short* ap = &t_hi[l31 * TS + kc * 16 + kh * 8];
        short8 ah = *(const short8*)ap;
        short8 al = *(const short8*)(ap + 32 * TS);
        acc2 = __builtin_amdgcn_mfma_f32_32x32x16_bf16(ah, bh, acc2, 0, 0, 0);
        acc2 = __builtin_amdgcn_mfma_f32_32x32x16_bf16(al, bh, acc2, 0, 0, 0);
        acc2 = __builtin_amdgcn_mfma_f32_32x32x16_bf16(ah, bl, acc2, 0, 0, 0);
    }
#pragma unroll
    for (int reg = 0; reg < 16; reg++) {
        int row = (reg & 3) + 8 * (reg >> 2) + 4 * kh;
        unsigned h, l;
        splitt(selu_f(acc2[reg]), h, l);
        size_t o = (size_t)(n0 + row) * 128 + col;
        goh_s[o] = (short)h;
        gol_s[o] = (short)l;
    }
}

// Wf chain on first-half edges: q_new = q_old + selu(selu(lam@Wf1)@Wf2)@Wf3;
// antisymmetrize; ALSO computes hl for both halves (hl[e+E2] = -hl[e]).
__global__ __launch_bounds__(256) void k_wf_mfma(
    const unsigned* __restrict__ gh_u, const unsigned* __restrict__ gl_u,
    const unsigned* __restrict__ zh_u, const unsigned* __restrict__ zl_u,
    const short* __restrict__ W1h, const short* __restrict__ W1l,
    const short* __restrict__ W2h, const short* __restrict__ W2l,
    const float* __restrict__ W3 /*[128]*/,
    const int* __restrict__ sndr, const int* __restrict__ rcvr,
    const float* __restrict__ r,
    float* __restrict__ qh, float* __restrict__ hl) {
    __shared__ short smem[2 * 32 * MS_E];
    __shared__ float red[32 * 4];
    short* m_hi = smem;
    short* m_lo = smem + 32 * MS_E;
    short* t_hi = smem;
    short* t_lo = smem + 32 * TS;
    const int tid = threadIdx.x;
    const int bi = blockIdx.x;
    const int x7 = bi & 7, jj = bi >> 3;
    const int fi0 = ((x7 >> 1) * 500 + (x7 & 1) * 250 + jj) * 32;
    const int b = fi0 / E2c;
    const int ebase = b * EPGc - b * E2c;     // e = ebase + fi
    const int lane = tid & 63, wave = tid >> 6;

    for (int t = wave; t < 96; t += 4) {
        int row = t & 31, region = t >> 5;
        int e = ebase + fi0 + row;
        size_t o;
        const unsigned *ph, *pl;
        if (region == 0)      { o = (size_t)sndr[e] * 64; ph = gh_u; pl = gl_u; }
        else if (region == 1) { o = (size_t)rcvr[e] * 64; ph = gh_u; pl = gl_u; }
        else                  { o = (size_t)e * 64;       ph = zh_u; pl = zl_u; }
        load_lds4(ph + o + lane, &m_hi[row * MS_E + region * 128]);
        load_lds4(pl + o + lane, &m_lo[row * MS_E + region * 128]);
    }
    __syncthreads();

    const int ct = wave;
    const int l31 = lane & 31, kh = lane >> 5;
    const int col = ct * 32 + l31;

    f32x16 acc;
#pragma unroll
    for (int i = 0; i < 16; i++) acc[i] = 0.0f;
#pragma unroll 4
    for (int kc = 0; kc < 24; kc++) {
        size_t wo = ((size_t)(ct * 24 + kc) * 64 + lane) * 8;
        short8 bh = *(const short8*)&W1h[wo];
        short8 bl = *(const short8*)&W1l[wo];
        const short* ap = &m_hi[l31 * MS_E + kc * 16 + kh * 8];
        short8 ah = *(const short8*)ap;
        short8 al = *(const short8*)(ap + 32 * MS_E);
        acc = __builtin_amdgcn_mfma_f32_32x32x16_bf16(ah, bh, acc, 0, 0, 0);
        acc = __builtin_amdgcn_mfma_f32_32x32x16_bf16(al, bh, acc, 0, 0, 0);
        acc = __builtin_amdgcn_mfma_f32_32x32x16_bf16(ah, bl, acc, 0, 0, 0);
    }
    __syncthreads();
#pragma unroll
    for (int reg = 0; reg < 16; reg++) {
        int row = (reg & 3) + 8 * (reg >> 2) + 4 * kh;
        unsigned h, l;
        splitt(selu_f(acc[reg]), h, l);
        t_hi[row * TS + col] = (short)h;
        t_lo[row * TS + col] = (short)l;
    }
    __syncthreads();

    f32x16 acc2;
#pragma unroll
    for (int i = 0; i < 16; i++) acc2[i] = 0.0f;
#pragma unroll
    for (int kc = 0; kc < 8; kc++) {
        size_t wo = ((size_t)(ct * 8 + kc) * 64 + lane) * 8;
        short8 bh = *(const short8*)&W2h[wo];
        short8 bl = *(const short8*)&W2l[wo];
        const short* ap = &t_hi[l31 * TS + kc * 16 + kh * 8];
        short8 ah = *(const short8*)ap;
        short8 al = *(const short8*)(ap + 32 * TS);
        acc2 = __builtin_amdgcn_mfma_f32_32x32x16_bf16(ah, bh, acc2, 0, 0, 0);
        acc2 = __builtin_amdgcn_mfma_f32_32x32x16_bf16(al, bh, acc2, 0, 0, 0);
        acc2 = __builtin_amdgcn_mfma_f32_32x32x16_bf16(ah, bl, acc2, 0, 0, 0);
    }
    // f[row] = sum_col selu(out[row][col]) * W3[col]
    float w3 = W3[col];
    float p[16];
#pragma unroll
    for (int reg = 0; reg < 16; reg++) p[reg] = selu_f(acc2[reg]) * w3;
    // reduce over the 32 cols (lane bits 0..4; stays within each 32-lane half)
#pragma unroll
    for (int off = 1; off < 32; off <<= 1) {
#pragma unroll
        for (int i = 0; i < 16; i++) p[i] += __shfl_xor(p[i], off, 64);
    }
    if (l31 == 0) {
#pragma unroll
        for (int reg = 0; reg < 16; reg++) {
            int row = (reg & 3) + 8 * (reg >> 2) + 4 * kh;
            red[row * 4 + ct] = p[reg];
        }
    }
    __syncthreads();
    if (tid < 32) {
        float f = red[tid * 4] + red[tid * 4 + 1] + red[tid * 4 + 2] + red[tid * 4 + 3];
        int e = ebase + fi0 + tid;
        float qn = qh[e] + f;
        qh[e] = qn;
        qh[e + E2c] = -qn;
        float hv = r[e] * signf(qn) * __powf(fabsf(qn), PEXPc);
        hl[e] = hv;
        hl[e + E2c] = -hv;
    }
}

// ---------------- host orchestration ----------------

extern "C" void kernel_launch(void* const* d_in, const int* in_sizes, int n_in,
                              void* d_out, int out_size, void* d_ws, size_t ws_size,
                              hipStream_t stream) {
    const float* x   = (const float*)d_in[0];
    const float* r   = (const float*)d_in[1];
    const float* Wni = (const float*)d_in[2];
    const float* Wei = (const float*)d_in[3];
    const float* Wf1 = (const float*)d_in[4];
    const float* Wf2 = (const float*)d_in[5];
    const float* Wf3 = (const float*)d_in[6];
    const float* We1 = (const float*)d_in[7];   // (3,384,128)
    const float* We2 = (const float*)d_in[8];   // (3,128,128)
    const float* Wn1 = (const float*)d_in[9];   // (3,256,128)
    const float* Wn2 = (const float*)d_in[10];  // (3,128,128)
    const int* sndr  = (const int*)d_in[11];
    const int* rcvr  = (const int*)d_in[12];
    float* out = (float*)d_out;

    char* wp = (char*)d_ws;
    auto carve = [&](size_t bytes) -> void* {
        void* ret = (void*)wp;
        wp += (bytes + 255) & ~(size_t)255;
        return ret;
    };
    unsigned* gh_u = (unsigned*)carve((size_t)NNc * 64 * 4);
    unsigned* gl_u = (unsigned*)carve((size_t)NNc * 64 * 4);
    unsigned* zAh  = (unsigned*)carve((size_t)NEc * 64 * 4);
    unsigned* zAl  = (unsigned*)carve((size_t)NEc * 64 * 4);
    unsigned* zBh  = (unsigned*)carve((size_t)NEc * 64 * 4);
    unsigned* zBl  = (unsigned*)carve((size_t)NEc * 64 * 4);
    float* qh     = (float*)carve((size_t)NEc * 4);
    float* qt     = (float*)carve((size_t)NEc * 4);
    float* hl     = (float*)carve((size_t)NEc * 4);
    float* hA     = (float*)carve((size_t)NNc * 4);
    float* hB     = (float*)carve((size_t)NNc * 4);
    int*   deg    = (int*)carve((size_t)NNc * 4);
    int*   cursor = (int*)carve((size_t)NNc * 4);
    int*   rowst  = (int*)carve((size_t)(NNc + 1) * 4);
    int*   part   = (int*)carve((size_t)NSB * 4);
    int2*  csr_se = (int2*)carve((size_t)NEc * 8);
    short* we1h   = (short*)carve((size_t)3 * 128 * 384 * 2);
    short* we1l   = (short*)carve((size_t)3 * 128 * 384 * 2);
    short* we2h   = (short*)carve((size_t)3 * 128 * 128 * 2);
    short* we2l   = (short*)carve((size_t)3 * 128 * 128 * 2);
    short* wn1h   = (short*)carve((size_t)3 * 128 * 256 * 2);
    short* wn1l   = (short*)carve((size_t)3 * 128 * 256 * 2);
    short* wn2h   = (short*)carve((size_t)3 * 128 * 128 * 2);
    short* wn2l   = (short*)carve((size_t)3 * 128 * 128 * 2);
    short* wf1h   = (short*)carve((size_t)128 * 384 * 2);
    short* wf1l   = (short*)carve((size_t)128 * 384 * 2);
    short* wf2h   = (short*)carve((size_t)128 * 128 * 2);
    short* wf2l   = (short*)carve((size_t)128 * 128 * 2);

    const int TB = 256;
    const int gN  = (NNc + TB - 1) / TB;
    const int gE  = (NEc + TB - 1) / TB;

    // fragment-linear weight planes for 32x32 MFMA (nkc = K/16, nct = 4)
    for (int i = 0; i < 3; i++) {
        k_wconv_frag<<<(4 * 24 * 64 + 255) / 256, TB, 0, stream>>>(We1 + (size_t)i * 384 * 128, we1h + (size_t)i * 128 * 384, we1l + (size_t)i * 128 * 384, 24);
        k_wconv_frag<<<(4 * 8 * 64 + 255) / 256, TB, 0, stream>>>(We2 + (size_t)i * 128 * 128, we2h + (size_t)i * 128 * 128, we2l + (size_t)i * 128 * 128, 8);
        k_wconv_frag<<<(4 * 16 * 64 + 255) / 256, TB, 0, stream>>>(Wn1 + (size_t)i * 256 * 128, wn1h + (size_t)i * 128 * 256, wn1l + (size_t)i * 128 * 256, 16);
        k_wconv_frag<<<(4 * 8 * 64 + 255) / 256, TB, 0, stream>>>(Wn2 + (size_t)i * 128 * 128, wn2h + (size_t)i * 128 * 128, wn2l + (size_t)i * 128 * 128, 8);
    }
    k_wconv_frag<<<(4 * 24 * 64 + 255) / 256, TB, 0, stream>>>(Wf1, wf1h, wf1l, 24);
    k_wconv_frag<<<(4 * 8 * 64 + 255) / 256, TB, 0, stream>>>(Wf2, wf2h, wf2l, 8);

    // CSR build (multi-block scan)
    k_zero_i<<<gN, TB, 0, stream>>>(deg, NNc);
    k_count<<<gE, TB, 0, stream>>>(rcvr, deg);
    k_scan1<<<NSB, TB, 0, stream>>>(deg, part);
    k_scan2<<<1, TB, 0, stream>>>(part);
    k_scan3<<<NSB, TB, 0, stream>>>(deg, part, rowst, cursor);
    k_scatter<<<gE, TB, 0, stream>>>(sndr, rcvr, cursor, csr_se);

    // initial flows
    k_qinit<<<gE, TB, 0, stream>>>(x, r, sndr, rcvr, qh, qt);

    const int gH = (NNc + 63) / 64;
    for (int kit = 0; kit < 4; kit++) {
        k_node_in_f<<<(NNc + 3) / 4, TB, 0, stream>>>(qh, rowst, csr_se, x, Wni, gh_u, gl_u);
        unsigned *zin_h = zAh, *zin_l = zAl, *zout_h = zAh, *zout_l = zAl;
        for (int i = 0; i < 3; i++) {
            zin_h = zout_h; zin_l = zout_l;
            zout_h = (i & 1) ? zAh : zBh;
            zout_l = (i & 1) ? zAl : zBl;
            k_edge_mlp_mfma<<<NEc / 32, 256, 0, stream>>>(
                gh_u, gl_u, zin_h, zin_l, (short*)zout_h, (short*)zout_l,
                we1h + (size_t)i * 128 * 384, we1l + (size_t)i * 128 * 384,
                we2h + (size_t)i * 128 * 128, we2l + (size_t)i * 128 * 128,
                sndr, rcvr, qt, qh, Wei, (i == 0) ? 1 : 0);
            k_node_mlp_mfma<<<NNc / 32, 256, 0, stream>>>(
                gh_u, gl_u, (short*)gh_u, (short*)gl_u, zout_h, zout_l, rowst, csr_se,
                wn1h + (size_t)i * 128 * 256, wn1l + (size_t)i * 128 * 256,
                wn2h + (size_t)i * 128 * 128, wn2l + (size_t)i * 128 * 128);
        }
        k_wf_mfma<<<(4 * E2c) / 32, 256, 0, stream>>>(
            gh_u, gl_u, zout_h, zout_l, wf1h, wf1l, wf2h, wf2l, Wf3, sndr, rcvr,
            r, qh, hl);
        // head propagation: 6 iterations; first reads h_star straight from x (stride 2)
        const float* hin = x; int hstride = 2;
        float* cur = hA;
        for (int jh = 0; jh < 6; jh++) {
            float* dst = (jh == 5) ? ((kit == 3) ? out : hB) : cur;
            k_head_iter<<<gH, 64, 0, stream>>>(x, hin, hstride, hl, rowst, csr_se, dst);
            hin = dst; hstride = 1;
            cur = (dst == hA) ? hB : hA;
        }
        if (kit < 3) k_flows_q<<<gE, TB, 0, stream>>>(hB, r, sndr, rcvr, qt);
    }
}

// Round 11
// 2074.371 us; speedup vs baseline: 1.5056x; 1.5056x over previous
//
#include <hip/hip_runtime.h>
#include <hip/hip_bf16.h>
#include <math.h>

// Problem constants
#define NPGc  10000
#define EPGc  32000
#define MLc   128
#define NNc   40000      // N
#define NEc   128000     // E
#define E2c   16000      // EPG/2
#define ZETAc 1e-6f
#define INVPc 0.53995680345572354f   // 1/1.852
#define PEXPc 1.852f
#define NSB   ((NNc + 255) / 256)    // 157 scan blocks

typedef __attribute__((ext_vector_type(8))) short short8;   // 8 bf16 (4 VGPRs)
typedef __attribute__((ext_vector_type(4))) float f32x4;    // MFMA acc

// fast selu: __expf -> v_exp_f32
__device__ __forceinline__ float selu_f(float x) {
    float e = __expf(x) - 1.0f;
    return 1.0507009873554805f * (x > 0.0f ? x : 1.6732632423543772f * e);
}
// cheap split fp32 -> (hi, lo): hi = truncated top-16 bits (exact rem), lo = RNE(rem).
// product error ~2^-17 relative: far below the bf16-grade threshold.
__device__ __forceinline__ void splitt(float v, unsigned& hi, unsigned& lo) {
    unsigned u = __float_as_uint(v);
    hi = u >> 16;
    float rem = v - __uint_as_float(u & 0xffff0000u);
    __hip_bfloat16 l = __float2bfloat16(rem);
    lo = (unsigned short)*reinterpret_cast<short*>(&l);
}
__device__ __forceinline__ float signf(float x) {
    return (x > 0.0f) ? 1.0f : (x < 0.0f ? -1.0f : 0.0f);
}

// async global->LDS: 64 lanes x 4B, wave-uniform LDS base + lane*4
__device__ __forceinline__ void load_lds4(const unsigned* src, short* dst) {
    __builtin_amdgcn_global_load_lds(
        (const __attribute__((address_space(1))) unsigned*)src,
        (__attribute__((address_space(3))) unsigned*)dst, 4, 0, 0);
}

// ---------------- weight convert+split into MFMA B-FRAGMENT-LINEAR layout ------------
// B-frag for mfma_16x16x32: n = ct*16 + (lane&15), k = kc*32 + (lane>>4)*8 + j.
__global__ void k_wconv_frag(const float* __restrict__ src, short* __restrict__ dh,
                             short* __restrict__ dl, int nkc /* = K/32 */) {
    int gid = blockIdx.x * 256 + threadIdx.x;   // one thread per (frag, lane)
    int total = 8 * nkc * 64;                   // ct(8) x kc(nkc) x lane(64)
    if (gid >= total) return;
    int lane = gid & 63;
    int frag = gid >> 6;
    int kc = frag % nkc;
    int ct = frag / nkc;
    int col = ct * 16 + (lane & 15);
    int kbase = kc * 32 + (lane >> 4) * 8;
    size_t o = (size_t)gid * 8;
#pragma unroll
    for (int j = 0; j < 8; j++) {
        unsigned h, l;
        splitt(src[(size_t)(kbase + j) * 128 + col], h, l);
        dh[o + j] = (short)h;
        dl[o + j] = (short)l;
    }
}

// ---------------- CSR build (by rcvr) ----------------
__global__ void k_zero_i(int* p, int n) {
    int i = blockIdx.x * 256 + threadIdx.x;
    if (i < n) p[i] = 0;
}
__global__ void k_count(const int* __restrict__ rcvr, int* __restrict__ deg) {
    int e = blockIdx.x * 256 + threadIdx.x;
    if (e < NEc) atomicAdd(&deg[rcvr[e]], 1);
}
// 3-phase multi-block exclusive scan
__global__ void k_scan1(const int* __restrict__ deg, int* __restrict__ partial) {
    __shared__ int buf[256];
    int t = threadIdx.x;
    int i = blockIdx.x * 256 + t;
    buf[t] = (i < NNc) ? deg[i] : 0;
    __syncthreads();
    for (int off = 128; off > 0; off >>= 1) {
        if (t < off) buf[t] += buf[t + off];
        __syncthreads();
    }
    if (t == 0) partial[blockIdx.x] = buf[0];
}
__global__ void k_scan2(int* __restrict__ partial) {
    __shared__ int buf[256];
    int t = threadIdx.x;
    int v = (t < NSB) ? partial[t] : 0;
    buf[t] = v;
    __syncthreads();
    for (int off = 1; off < 256; off <<= 1) {
        int u = (t >= off) ? buf[t - off] : 0;
        __syncthreads();
        buf[t] += u;
        __syncthreads();
    }
    if (t < NSB) partial[t] = buf[t] - v;   // exclusive
}
__global__ void k_scan3(const int* __restrict__ deg, const int* __restrict__ partial,
                        int* __restrict__ rowstart, int* __restrict__ cursor) {
    __shared__ int buf[256];
    int t = threadIdx.x;
    int i = blockIdx.x * 256 + t;
    int v = (i < NNc) ? deg[i] : 0;
    buf[t] = v;
    __syncthreads();
    for (int off = 1; off < 256; off <<= 1) {
        int u = (t >= off) ? buf[t - off] : 0;
        __syncthreads();
        buf[t] += u;
        __syncthreads();
    }
    int excl = partial[blockIdx.x] + buf[t] - v;
    if (i < NNc) { rowstart[i] = excl; cursor[i] = excl; }
    if (i == NNc - 1) rowstart[NNc] = excl + v;
}
__global__ void k_scatter(const int* __restrict__ sndr, const int* __restrict__ rcvr,
                          int* __restrict__ cursor, int2* __restrict__ csr_se) {
    int e = blockIdx.x * 256 + threadIdx.x;
    if (e >= NEc) return;
    int rv = rcvr[e];
    int p = atomicAdd(&cursor[rv], 1);
    csr_se[p] = make_int2(sndr[e], e);
}

// ---------------- flows / elementwise ----------------
__global__ void k_qinit(const float* __restrict__ x, const float* __restrict__ r,
                        const int* __restrict__ sndr, const int* __restrict__ rcvr,
                        float* __restrict__ qh, float* __restrict__ qt) {
    int e = blockIdx.x * 256 + threadIdx.x;
    if (e >= NEc) return;
    float hv = x[2 * sndr[e]] - x[2 * rcvr[e]];
    float q = signf(hv) * __powf((fabsf(hv) + ZETAc) / (r[e] + ZETAc), INVPc);
    qh[e] = q; qt[e] = q;
}
__global__ void k_flows_q(const float* __restrict__ h, const float* __restrict__ r,
                          const int* __restrict__ sndr, const int* __restrict__ rcvr,
                          float* __restrict__ qt) {
    int e = blockIdx.x * 256 + threadIdx.x;
    if (e >= NEc) return;
    float hv = h[sndr[e]] - h[rcvr[e]];
    qt[e] = signf(hv) * __powf((fabsf(hv) + ZETAc) / (r[e] + ZETAc), INVPc);
}

// node-in, fused segsum: one WAVE per node. Produces split-selu g planes.
__global__ __launch_bounds__(256) void k_node_in_f(
    const float* __restrict__ qh, const int* __restrict__ rowstart,
    const int2* __restrict__ csr_se, const float* __restrict__ x,
    const float* __restrict__ W /*2x128*/,
    unsigned* __restrict__ gh_u, unsigned* __restrict__ gl_u) {
    const int tid = threadIdx.x;
    const int lane = tid & 63;
    const int n = blockIdx.x * 4 + (tid >> 6);
    if (n >= NNc) return;
    int p0 = rowstart[n], p1 = rowstart[n + 1];
    float s = 0.0f;
    for (int p = p0 + lane; p < p1; p += 64) s += qh[csr_se[p].y];
#pragma unroll
    for (int off = 1; off < 64; off <<= 1) s += __shfl_xor(s, off, 64);
    float s0 = selu_f(s);
    float s1 = selu_f(x[2 * n + 1]);
    int c = lane * 2;
    float g0 = s0 * W[c]     + s1 * W[MLc + c];
    float g1 = s0 * W[c + 1] + s1 * W[MLc + c + 1];
    unsigned h0, l0, h1, l1;
    splitt(selu_f(g0), h0, l0);
    splitt(selu_f(g1), h1, l1);
    gh_u[(size_t)n * 64 + lane] = h0 | (h1 << 16);
    gl_u[(size_t)n * 64 + lane] = l0 | (l1 << 16);
}

// one head-propagation iteration, CSR gather; hin has stride (2 for x, 1 for h buf)
__global__ __launch_bounds__(64) void k_head_iter(
    const float* __restrict__ x, const float* __restrict__ hin, int hstride,
    const float* __restrict__ hl, const int* __restrict__ rowstart,
    const int2* __restrict__ csr_se, float* __restrict__ hout) {
    int n = blockIdx.x * 64 + threadIdx.x;
    if (n >= NNc) return;
    float hv = hin[(size_t)n * hstride];
    float m = -3.0e38f;
    int p0 = rowstart[n], p1 = rowstart[n + 1];
    for (int p = p0; p < p1; p++) {
        int2 se = csr_se[p];
        m = fmaxf(m, hin[(size_t)se.x * hstride] - hl[se.y]);
    }
    float a = (m > -1e30f) ? m : hv;
    float hstar = x[2 * n];
    hout[n] = (hstar != 0.0f) ? hstar : fmaxf(hv, a);
}

// ---------------- split-bf16 MFMA MLP kernels ----------------
// Inputs arrive as pre-split selu planes (h/l shorts, 2 cols packed per dword).
// Weights fragment-linear. Staging via global_load_lds (zero-VALU data movement).
// 32-row tile, 512 threads = 8 waves; wave = 16-col tile x both 16-row tiles
// (2 independent accumulator chains per wave for MFMA ILP).
// A-frag: row=lane&15, k=quad*8+j. C/D: col=lane&15, row=quad*4+reg.
// XCD swizzle: blocks on the same XCD (bi&7) handle the same batch group.

#define MS_E 392   // 384+8 shorts
#define MS_N 264   // 256+8
#define TS   136   // 128+8

__global__ __launch_bounds__(512) void k_edge_mlp_mfma(
    const unsigned* __restrict__ gh_u, const unsigned* __restrict__ gl_u,
    const unsigned* __restrict__ zh_u, const unsigned* __restrict__ zl_u,
    short* __restrict__ zoh_s, short* __restrict__ zol_s,
    const short* __restrict__ W1h, const short* __restrict__ W1l,
    const short* __restrict__ W2h, const short* __restrict__ W2l,
    const int* __restrict__ sndr, const int* __restrict__ rcvr,
    const float* __restrict__ qt, const float* __restrict__ qh,
    const float* __restrict__ Wei, int zmode) {
    __shared__ short smem[2 * 32 * MS_E];        // 50176 B
    short* m_hi = smem;
    short* m_lo = smem + 32 * MS_E;
    short* t_hi = smem;                          // alias front (post-barrier)
    short* t_lo = smem + 32 * TS;
    const int tid = threadIdx.x;
    const int bi = blockIdx.x;
    const int x7 = bi & 7, jj = bi >> 3;
    const int e0 = ((x7 >> 1) * 1000 + (x7 & 1) * 500 + jj) * 32;   // XCD swizzle
    const int lane = tid & 63, wave = tid >> 6;

    if (zmode == 0) {
        for (int t = wave; t < 96; t += 8) {
            int row = t & 31, region = t >> 5;
            int e = e0 + row;
            size_t o;
            const unsigned *ph, *pl;
            if (region == 0)      { o = (size_t)sndr[e] * 64; ph = gh_u; pl = gl_u; }
            else if (region == 1) { o = (size_t)rcvr[e] * 64; ph = gh_u; pl = gl_u; }
            else                  { o = (size_t)e * 64;       ph = zh_u; pl = zl_u; }
            load_lds4(ph + o + lane, &m_hi[row * MS_E + region * 128]);
            load_lds4(pl + o + lane, &m_lo[row * MS_E + region * 128]);
        }
    } else {
        for (int t = wave; t < 64; t += 8) {
            int row = t & 31, region = t >> 5;
            int e = e0 + row;
            size_t o = (region == 0) ? (size_t)sndr[e] * 64 : (size_t)rcvr[e] * 64;
            load_lds4(gh_u + o + lane, &m_hi[row * MS_E + region * 128]);
            load_lds4(gl_u + o + lane, &m_lo[row * MS_E + region * 128]);
        }
        for (int idx = tid; idx < 32 * 64; idx += 512) {
            int row = idx >> 6, cp = idx & 63;
            int e = e0 + row;
            float sqt = selu_f(qt[e]), sqh = selu_f(qh[e]);
            int c = 2 * cp;
            float z0 = sqt * Wei[c]     + sqh * Wei[MLc + c];
            float z1 = sqt * Wei[c + 1] + sqh * Wei[MLc + c + 1];
            unsigned h0, l0, h1, l1;
            splitt(selu_f(z0), h0, l0);
            splitt(selu_f(z1), h1, l1);
            int k = 256 + 2 * cp;
            *(unsigned*)&m_hi[row * MS_E + k] = h0 | (h1 << 16);
            *(unsigned*)&m_lo[row * MS_E + k] = l0 | (l1 << 16);
        }
    }
    __syncthreads();

    const int ct = wave;
    const int l15 = lane & 15, quad = lane >> 4;
    const int col = ct * 16 + l15;

    f32x4 acc[2];
    acc[0] = (f32x4){0.f, 0.f, 0.f, 0.f};
    acc[1] = (f32x4){0.f, 0.f, 0.f, 0.f};
#pragma unroll 4
    for (int kc = 0; kc < 12; kc++) {
        size_t wo = ((size_t)(ct * 12 + kc) * 64 + lane) * 8;   // fragment-linear
        short8 bh = *(const short8*)&W1h[wo];
        short8 bl = *(const short8*)&W1l[wo];
#pragma unroll
        for (int rt = 0; rt < 2; rt++) {
            const short* ap = &m_hi[(rt * 16 + l15) * MS_E + kc * 32 + quad * 8];
            short8 ah = *(const short8*)ap;
            short8 al = *(const short8*)(ap + 32 * MS_E);
            acc[rt] = __builtin_amdgcn_mfma_f32_16x16x32_bf16(ah, bh, acc[rt], 0, 0, 0);
            acc[rt] = __builtin_amdgcn_mfma_f32_16x16x32_bf16(al, bh, acc[rt], 0, 0, 0);
            acc[rt] = __builtin_amdgcn_mfma_f32_16x16x32_bf16(ah, bl, acc[rt], 0, 0, 0);
        }
    }
    __syncthreads();
#pragma unroll
    for (int rt = 0; rt < 2; rt++) {
#pragma unroll
        for (int rr = 0; rr < 4; rr++) {
            unsigned h, l;
            splitt(selu_f(acc[rt][rr]), h, l);
            t_hi[(rt * 16 + quad * 4 + rr) * TS + col] = (short)h;
            t_lo[(rt * 16 + quad * 4 + rr) * TS + col] = (short)l;
        }
    }
    __syncthreads();

    f32x4 acc2[2];
    acc2[0] = (f32x4){0.f, 0.f, 0.f, 0.f};
    acc2[1] = (f32x4){0.f, 0.f, 0.f, 0.f};
#pragma unroll
    for (int kc = 0; kc < 4; kc++) {
        size_t wo = ((size_t)(ct * 4 + kc) * 64 + lane) * 8;
        short8 bh = *(const short8*)&W2h[wo];
        short8 bl = *(const short8*)&W2l[wo];
#pragma unroll
        for (int rt = 0; rt < 2; rt++) {
            const short* ap = &t_hi[(rt * 16 + l15) * TS + kc * 32 + quad * 8];
            short8 ah = *(const short8*)ap;
            short8 al = *(const short8*)(ap + 32 * TS);
            acc2[rt] = __builtin_amdgcn_mfma_f32_16x16x32_bf16(ah, bh, acc2[rt], 0, 0, 0);
            acc2[rt] = __builtin_amdgcn_mfma_f32_16x16x32_bf16(al, bh, acc2[rt], 0, 0, 0);
            acc2[rt] = __builtin_amdgcn_mfma_f32_16x16x32_bf16(ah, bl, acc2[rt], 0, 0, 0);
        }
    }
#pragma unroll
    for (int rt = 0; rt < 2; rt++) {
#pragma unroll
        for (int rr = 0; rr < 4; rr++) {
            unsigned h, l;
            splitt(selu_f(acc2[rt][rr]), h, l);
            size_t o = (size_t)(e0 + rt * 16 + quad * 4 + rr) * 128 + col;
            zoh_s[o] = (short)h;
            zol_s[o] = (short)l;
        }
    }
}

// node MLP: g-gather via global_load_lds + selu-space segment max of z planes
__global__ __launch_bounds__(512) void k_node_mlp_mfma(
    const unsigned* __restrict__ gh_u, const unsigned* __restrict__ gl_u,
    short* __restrict__ goh_s, short* __restrict__ gol_s,
    const unsigned* __restrict__ zh_u, const unsigned* __restrict__ zl_u,
    const int* __restrict__ rowstart, const int2* __restrict__ csr_se,
    const short* __restrict__ W1h, const short* __restrict__ W1l,
    const short* __restrict__ W2h, const short* __restrict__ W2l) {
    __shared__ short smem[2 * 32 * MS_N];        // 33792 B
    short* m_hi = smem;
    short* m_lo = smem + 32 * MS_N;
    short* t_hi = smem;
    short* t_lo = smem + 32 * TS;
    const int tid = threadIdx.x;
    const int n0 = blockIdx.x * 32;
    const int lane = tid & 63, wave = tid >> 6;

    for (int t = wave; t < 32; t += 8) {
        int n = n0 + t;
        load_lds4(gh_u + (size_t)n * 64 + lane, &m_hi[t * MS_N]);
        load_lds4(gl_u + (size_t)n * 64 + lane, &m_lo[t * MS_N]);
    }
    for (int idx = tid; idx < 32 * 64; idx += 512) {
        int row = idx >> 6, cp = idx & 63;
        int n = n0 + row;
        int p0 = rowstart[n], p1 = rowstart[n + 1];
        float b0 = -3.0e38f, b1 = -3.0e38f;
        unsigned bh0 = 0, bl0 = 0, bh1 = 0, bl1 = 0;  // default split(0)
        for (int p = p0; p < p1; p++) {
            size_t o = (size_t)csr_se[p].y * 64 + cp;
            unsigned vh = zh_u[o], vl = zl_u[o];
            float f0 = __uint_as_float(vh << 16) + __uint_as_float(vl << 16);
            float f1 = __uint_as_float(vh & 0xffff0000u) + __uint_as_float(vl & 0xffff0000u);
            if (f0 > b0) { b0 = f0; bh0 = vh & 0xffffu; bl0 = vl & 0xffffu; }
            if (f1 > b1) { b1 = f1; bh1 = vh & 0xffff0000u; bl1 = vl & 0xffff0000u; }
        }
        int k = 128 + 2 * cp;
        *(unsigned*)&m_hi[row * MS_N + k] = bh0 | bh1;
        *(unsigned*)&m_lo[row * MS_N + k] = bl0 | bl1;
    }
    __syncthreads();

    const int ct = wave;
    const int l15 = lane & 15, quad = lane >> 4;
    const int col = ct * 16 + l15;

    f32x4 acc[2];
    acc[0] = (f32x4){0.f, 0.f, 0.f, 0.f};
    acc[1] = (f32x4){0.f, 0.f, 0.f, 0.f};
#pragma unroll 4
    for (int kc = 0; kc < 8; kc++) {
        size_t wo = ((size_t)(ct * 8 + kc) * 64 + lane) * 8;
        short8 bh = *(const short8*)&W1h[wo];
        short8 bl = *(const short8*)&W1l[wo];
#pragma unroll
        for (int rt = 0; rt < 2; rt++) {
            const short* ap = &m_hi[(rt * 16 + l15) * MS_N + kc * 32 + quad * 8];
            short8 ah = *(const short8*)ap;
            short8 al = *(const short8*)(ap + 32 * MS_N);
            acc[rt] = __builtin_amdgcn_mfma_f32_16x16x32_bf16(ah, bh, acc[rt], 0, 0, 0);
            acc[rt] = __builtin_amdgcn_mfma_f32_16x16x32_bf16(al, bh, acc[rt], 0, 0, 0);
            acc[rt] = __builtin_amdgcn_mfma_f32_16x16x32_bf16(ah, bl, acc[rt], 0, 0, 0);
        }
    }
    __syncthreads();
#pragma unroll
    for (int rt = 0; rt < 2; rt++) {
#pragma unroll
        for (int rr = 0; rr < 4; rr++) {
            unsigned h, l;
            splitt(selu_f(acc[rt][rr]), h, l);
            t_hi[(rt * 16 + quad * 4 + rr) * TS + col] = (short)h;
            t_lo[(rt * 16 + quad * 4 + rr) * TS + col] = (short)l;
        }
    }
    __syncthreads();

    f32x4 acc2[2];
    acc2[0] = (f32x4){0.f, 0.f, 0.f, 0.f};
    acc2[1] = (f32x4){0.f, 0.f, 0.f, 0.f};
#pragma unroll
    for (int kc = 0; kc < 4; kc++) {
        size_t wo = ((size_t)(ct * 4 + kc) * 64 + lane) * 8;
        short8 bh = *(const short8*)&W2h[wo];
        short8 bl = *(const short8*)&W2l[wo];
#pragma unroll
        for (int rt = 0; rt < 2; rt++) {
            const short* ap = &t_hi[(rt * 16 + l15) * TS + kc * 32 + quad * 8];
            short8 ah = *(const short8*)ap;
            short8 al = *(const short8*)(ap + 32 * TS);
            acc2[rt] = __builtin_amdgcn_mfma_f32_16x16x32_bf16(ah, bh, acc2[rt], 0, 0, 0);
            acc2[rt] = __builtin_amdgcn_mfma_f32_16x16x32_bf16(al, bh, acc2[rt], 0, 0, 0);
            acc2[rt] = __builtin_amdgcn_mfma_f32_16x16x32_bf16(ah, bl, acc2[rt], 0, 0, 0);
        }
    }
#pragma unroll
    for (int rt = 0; rt < 2; rt++) {
#pragma unroll
        for (int rr = 0; rr < 4; rr++) {
            unsigned h, l;
            splitt(selu_f(acc2[rt][rr]), h, l);
            size_t o = (size_t)(n0 + rt * 16 + quad * 4 + rr) * 128 + col;
            goh_s[o] = (short)h;
            gol_s[o] = (short)l;
        }
    }
}

// Wf chain on first-half edges: q_new = q_old + selu(selu(lam@Wf1)@Wf2)@Wf3;
// antisymmetrize; ALSO computes hl for both halves (hl[e+E2] = -hl[e]).
__global__ __launch_bounds__(512) void k_wf_mfma(
    const unsigned* __restrict__ gh_u, const unsigned* __restrict__ gl_u,
    const unsigned* __restrict__ zh_u, const unsigned* __restrict__ zl_u,
    const short* __restrict__ W1h, const short* __restrict__ W1l,
    const short* __restrict__ W2h, const short* __restrict__ W2l,
    const float* __restrict__ W3 /*[128]*/,
    const int* __restrict__ sndr, const int* __restrict__ rcvr,
    const float* __restrict__ r,
    float* __restrict__ qh, float* __restrict__ hl) {
    __shared__ short smem[2 * 32 * MS_E];
    __shared__ float red[32 * 8];
    short* m_hi = smem;
    short* m_lo = smem + 32 * MS_E;
    short* t_hi = smem;
    short* t_lo = smem + 32 * TS;
    const int tid = threadIdx.x;
    const int bi = blockIdx.x;
    const int x7 = bi & 7, jj = bi >> 3;
    const int fi0 = ((x7 >> 1) * 500 + (x7 & 1) * 250 + jj) * 32;
    const int b = fi0 / E2c;
    const int ebase = b * EPGc - b * E2c;     // e = ebase + fi
    const int lane = tid & 63, wave = tid >> 6;

    for (int t = wave; t < 96; t += 8) {
        int row = t & 31, region = t >> 5;
        int e = ebase + fi0 + row;
        size_t o;
        const unsigned *ph, *pl;
        if (region == 0)      { o = (size_t)sndr[e] * 64; ph = gh_u; pl = gl_u; }
        else if (region == 1) { o = (size_t)rcvr[e] * 64; ph = gh_u; pl = gl_u; }
        else                  { o = (size_t)e * 64;       ph = zh_u; pl = zl_u; }
        load_lds4(ph + o + lane, &m_hi[row * MS_E + region * 128]);
        load_lds4(pl + o + lane, &m_lo[row * MS_E + region * 128]);
    }
    __syncthreads();

    const int ct = wave;
    const int l15 = lane & 15, quad = lane >> 4;
    const int col = ct * 16 + l15;

    f32x4 acc[2];
    acc[0] = (f32x4){0.f, 0.f, 0.f, 0.f};
    acc[1] = (f32x4){0.f, 0.f, 0.f, 0.f};
#pragma unroll 4
    for (int kc = 0; kc < 12; kc++) {
        size_t wo = ((size_t)(ct * 12 + kc) * 64 + lane) * 8;
        short8 bh = *(const short8*)&W1h[wo];
        short8 bl = *(const short8*)&W1l[wo];
#pragma unroll
        for (int rt = 0; rt < 2; rt++) {
            const short* ap = &m_hi[(rt * 16 + l15) * MS_E + kc * 32 + quad * 8];
            short8 ah = *(const short8*)ap;
            short8 al = *(const short8*)(ap + 32 * MS_E);
            acc[rt] = __builtin_amdgcn_mfma_f32_16x16x32_bf16(ah, bh, acc[rt], 0, 0, 0);
            acc[rt] = __builtin_amdgcn_mfma_f32_16x16x32_bf16(al, bh, acc[rt], 0, 0, 0);
            acc[rt] = __builtin_amdgcn_mfma_f32_16x16x32_bf16(ah, bl, acc[rt], 0, 0, 0);
        }
    }
    __syncthreads();
#pragma unroll
    for (int rt = 0; rt < 2; rt++) {
#pragma unroll
        for (int rr = 0; rr < 4; rr++) {
            unsigned h, l;
            splitt(selu_f(acc[rt][rr]), h, l);
            t_hi[(rt * 16 + quad * 4 + rr) * TS + col] = (short)h;
            t_lo[(rt * 16 + quad * 4 + rr) * TS + col] = (short)l;
        }
    }
    __syncthreads();

    f32x4 acc2[2];
    acc2[0] = (f32x4){0.f, 0.f, 0.f, 0.f};
    acc2[1] = (f32x4){0.f, 0.f, 0.f, 0.f};
#pragma unroll
    for (int kc = 0; kc < 4; kc++) {
        size_t wo = ((size_t)(ct * 4 + kc) * 64 + lane) * 8;
        short8 bh = *(const short8*)&W2h[wo];
        short8 bl = *(const short8*)&W2l[wo];
#pragma unroll
        for (int rt = 0; rt < 2; rt++) {
            const short* ap = &t_hi[(rt * 16 + l15) * TS + kc * 32 + quad * 8];
            short8 ah = *(const short8*)ap;
            short8 al = *(const short8*)(ap + 32 * TS);
            acc2[rt] = __builtin_amdgcn_mfma_f32_16x16x32_bf16(ah, bh, acc2[rt], 0, 0, 0);
            acc2[rt] = __builtin_amdgcn_mfma_f32_16x16x32_bf16(al, bh, acc2[rt], 0, 0, 0);
            acc2[rt] = __builtin_amdgcn_mfma_f32_16x16x32_bf16(ah, bl, acc2[rt], 0, 0, 0);
        }
    }
    float w3 = W3[col];
    float p[8];
#pragma unroll
    for (int rt = 0; rt < 2; rt++)
#pragma unroll
        for (int rr = 0; rr < 4; rr++) p[rt * 4 + rr] = selu_f(acc2[rt][rr]) * w3;
#pragma unroll
    for (int off = 1; off < 16; off <<= 1) {
#pragma unroll
        for (int i = 0; i < 8; i++) p[i] += __shfl_xor(p[i], off, 64);
    }
    if (l15 == 0) {
#pragma unroll
        for (int rt = 0; rt < 2; rt++)
#pragma unroll
            for (int rr = 0; rr < 4; rr++)
                red[(rt * 16 + quad * 4 + rr) * 8 + ct] = p[rt * 4 + rr];
    }
    __syncthreads();
    if (tid < 32) {
        float f = 0.0f;
#pragma unroll
        for (int c = 0; c < 8; c++) f += red[tid * 8 + c];
        int e = ebase + fi0 + tid;
        float qn = qh[e] + f;
        qh[e] = qn;
        qh[e + E2c] = -qn;
        float hv = r[e] * signf(qn) * __powf(fabsf(qn), PEXPc);
        hl[e] = hv;
        hl[e + E2c] = -hv;
    }
}

// ---------------- host orchestration ----------------

extern "C" void kernel_launch(void* const* d_in, const int* in_sizes, int n_in,
                              void* d_out, int out_size, void* d_ws, size_t ws_size,
                              hipStream_t stream) {
    const float* x   = (const float*)d_in[0];
    const float* r   = (const float*)d_in[1];
    const float* Wni = (const float*)d_in[2];
    const float* Wei = (const float*)d_in[3];
    const float* Wf1 = (const float*)d_in[4];
    const float* Wf2 = (const float*)d_in[5];
    const float* Wf3 = (const float*)d_in[6];
    const float* We1 = (const float*)d_in[7];   // (3,384,128)
    const float* We2 = (const float*)d_in[8];   // (3,128,128)
    const float* Wn1 = (const float*)d_in[9];   // (3,256,128)
    const float* Wn2 = (const float*)d_in[10];  // (3,128,128)
    const int* sndr  = (const int*)d_in[11];
    const int* rcvr  = (const int*)d_in[12];
    float* out = (float*)d_out;

    char* wp = (char*)d_ws;
    auto carve = [&](size_t bytes) -> void* {
        void* ret = (void*)wp;
        wp += (bytes + 255) & ~(size_t)255;
        return ret;
    };
    unsigned* gh_u = (unsigned*)carve((size_t)NNc * 64 * 4);
    unsigned* gl_u = (unsigned*)carve((size_t)NNc * 64 * 4);
    unsigned* zAh  = (unsigned*)carve((size_t)NEc * 64 * 4);
    unsigned* zAl  = (unsigned*)carve((size_t)NEc * 64 * 4);
    unsigned* zBh  = (unsigned*)carve((size_t)NEc * 64 * 4);
    unsigned* zBl  = (unsigned*)carve((size_t)NEc * 64 * 4);
    float* qh     = (float*)carve((size_t)NEc * 4);
    float* qt     = (float*)carve((size_t)NEc * 4);
    float* hl     = (float*)carve((size_t)NEc * 4);
    float* hA     = (float*)carve((size_t)NNc * 4);
    float* hB     = (float*)carve((size_t)NNc * 4);
    int*   deg    = (int*)carve((size_t)NNc * 4);
    int*   cursor = (int*)carve((size_t)NNc * 4);
    int*   rowst  = (int*)carve((size_t)(NNc + 1) * 4);
    int*   part   = (int*)carve((size_t)NSB * 4);
    int2*  csr_se = (int2*)carve((size_t)NEc * 8);
    short* we1h   = (short*)carve((size_t)3 * 128 * 384 * 2);
    short* we1l   = (short*)carve((size_t)3 * 128 * 384 * 2);
    short* we2h   = (short*)carve((size_t)3 * 128 * 128 * 2);
    short* we2l   = (short*)carve((size_t)3 * 128 * 128 * 2);
    short* wn1h   = (short*)carve((size_t)3 * 128 * 256 * 2);
    short* wn1l   = (short*)carve((size_t)3 * 128 * 256 * 2);
    short* wn2h   = (short*)carve((size_t)3 * 128 * 128 * 2);
    short* wn2l   = (short*)carve((size_t)3 * 128 * 128 * 2);
    short* wf1h   = (short*)carve((size_t)128 * 384 * 2);
    short* wf1l   = (short*)carve((size_t)128 * 384 * 2);
    short* wf2h   = (short*)carve((size_t)128 * 128 * 2);
    short* wf2l   = (short*)carve((size_t)128 * 128 * 2);

    const int TB = 256;
    const int gN  = (NNc + TB - 1) / TB;
    const int gE  = (NEc + TB - 1) / TB;

    // fragment-linear weight planes (nkc = K/32)
    for (int i = 0; i < 3; i++) {
        k_wconv_frag<<<(8 * 12 * 64 + 255) / 256, TB, 0, stream>>>(We1 + (size_t)i * 384 * 128, we1h + (size_t)i * 128 * 384, we1l + (size_t)i * 128 * 384, 12);
        k_wconv_frag<<<(8 * 4 * 64 + 255) / 256, TB, 0, stream>>>(We2 + (size_t)i * 128 * 128, we2h + (size_t)i * 128 * 128, we2l + (size_t)i * 128 * 128, 4);
        k_wconv_frag<<<(8 * 8 * 64 + 255) / 256, TB, 0, stream>>>(Wn1 + (size_t)i * 256 * 128, wn1h + (size_t)i * 128 * 256, wn1l + (size_t)i * 128 * 256, 8);
        k_wconv_frag<<<(8 * 4 * 64 + 255) / 256, TB, 0, stream>>>(Wn2 + (size_t)i * 128 * 128, wn2h + (size_t)i * 128 * 128, wn2l + (size_t)i * 128 * 128, 4);
    }
    k_wconv_frag<<<(8 * 12 * 64 + 255) / 256, TB, 0, stream>>>(Wf1, wf1h, wf1l, 12);
    k_wconv_frag<<<(8 * 4 * 64 + 255) / 256, TB, 0, stream>>>(Wf2, wf2h, wf2l, 4);

    // CSR build (multi-block scan)
    k_zero_i<<<gN, TB, 0, stream>>>(deg, NNc);
    k_count<<<gE, TB, 0, stream>>>(rcvr, deg);
    k_scan1<<<NSB, TB, 0, stream>>>(deg, part);
    k_scan2<<<1, TB, 0, stream>>>(part);
    k_scan3<<<NSB, TB, 0, stream>>>(deg, part, rowst, cursor);
    k_scatter<<<gE, TB, 0, stream>>>(sndr, rcvr, cursor, csr_se);

    // initial flows
    k_qinit<<<gE, TB, 0, stream>>>(x, r, sndr, rcvr, qh, qt);

    const int gH = (NNc + 63) / 64;
    for (int kit = 0; kit < 4; kit++) {
        k_node_in_f<<<(NNc + 3) / 4, TB, 0, stream>>>(qh, rowst, csr_se, x, Wni, gh_u, gl_u);
        unsigned *zin_h = zAh, *zin_l = zAl, *zout_h = zAh, *zout_l = zAl;
        for (int i = 0; i < 3; i++) {
            zin_h = zout_h; zin_l = zout_l;
            zout_h = (i & 1) ? zAh : zBh;
            zout_l = (i & 1) ? zAl : zBl;
            k_edge_mlp_mfma<<<NEc / 32, 512, 0, stream>>>(
                gh_u, gl_u, zin_h, zin_l, (short*)zout_h, (short*)zout_l,
                we1h + (size_t)i * 128 * 384, we1l + (size_t)i * 128 * 384,
                we2h + (size_t)i * 128 * 128, we2l + (size_t)i * 128 * 128,
                sndr, rcvr, qt, qh, Wei, (i == 0) ? 1 : 0);
            k_node_mlp_mfma<<<NNc / 32, 512, 0, stream>>>(
                gh_u, gl_u, (short*)gh_u, (short*)gl_u, zout_h, zout_l, rowst, csr_se,
                wn1h + (size_t)i * 128 * 256, wn1l + (size_t)i * 128 * 256,
                wn2h + (size_t)i * 128 * 128, wn2l + (size_t)i * 128 * 128);
        }
        k_wf_mfma<<<(4 * E2c) / 32, 512, 0, stream>>>(
            gh_u, gl_u, zout_h, zout_l, wf1h, wf1l, wf2h, wf2l, Wf3, sndr, rcvr,
            r, qh, hl);
        // head propagation: 6 iterations; first reads h_star straight from x (stride 2)
        const float* hin = x; int hstride = 2;
        float* cur = hA;
        for (int jh = 0; jh < 6; jh++) {
            float* dst = (jh == 5) ? ((kit == 3) ? out : hB) : cur;
            k_head_iter<<<gH, 64, 0, stream>>>(x, hin, hstride, hl, rowst, csr_se, dst);
            hin = dst; hstride = 1;
            cur = (dst == hA) ? hB : hA;
        }
        if (kit < 3) k_flows_q<<<gE, TB, 0, stream>>>(hB, r, sndr, rcvr, qt);
    }
}

// Round 12
// 1900.422 us; speedup vs baseline: 1.6434x; 1.0915x over previous
//
#include <hip/hip_runtime.h>
#include <hip/hip_bf16.h>
#include <math.h>

// Problem constants
#define NPGc  10000
#define EPGc  32000
#define MLc   128
#define NNc   40000      // N
#define NEc   128000     // E
#define E2c   16000      // EPG/2
#define ZETAc 1e-6f
#define INVPc 0.53995680345572354f   // 1/1.852
#define PEXPc 1.852f
#define NSB   ((NNc + 255) / 256)    // 157 scan blocks

typedef __attribute__((ext_vector_type(8))) short short8;   // 8 bf16 (4 VGPRs)
typedef __attribute__((ext_vector_type(4))) float f32x4;    // MFMA acc

// fast selu: __expf -> v_exp_f32
__device__ __forceinline__ float selu_f(float x) {
    float e = __expf(x) - 1.0f;
    return 1.0507009873554805f * (x > 0.0f ? x : 1.6732632423543772f * e);
}
// cheap split fp32 -> (hi, lo): hi = truncated top-16 bits (exact rem), lo = RNE(rem).
__device__ __forceinline__ void splitt(float v, unsigned& hi, unsigned& lo) {
    unsigned u = __float_as_uint(v);
    hi = u >> 16;
    float rem = v - __uint_as_float(u & 0xffff0000u);
    __hip_bfloat16 l = __float2bfloat16(rem);
    lo = (unsigned short)*reinterpret_cast<short*>(&l);
}
__device__ __forceinline__ float signf(float x) {
    return (x > 0.0f) ? 1.0f : (x < 0.0f ? -1.0f : 0.0f);
}
__device__ __forceinline__ int rfl(int v) { return __builtin_amdgcn_readfirstlane(v); }

// async global->LDS: 64 lanes x 4B, wave-uniform LDS base + lane*4
__device__ __forceinline__ void load_lds4(const unsigned* src, short* dst) {
    __builtin_amdgcn_global_load_lds(
        (const __attribute__((address_space(1))) unsigned*)src,
        (__attribute__((address_space(3))) unsigned*)dst, 4, 0, 0);
}

// ---------------- weight convert+split into MFMA B-FRAGMENT-LINEAR layout ------------
// B-frag for mfma_16x16x32: n = ct*16 + (lane&15), k = kc*32 + (lane>>4)*8 + j.
__global__ void k_wconv_frag(const float* __restrict__ src, short* __restrict__ dh,
                             short* __restrict__ dl, int nkc /* = K/32 */) {
    int gid = blockIdx.x * 256 + threadIdx.x;   // one thread per (frag, lane)
    int total = 8 * nkc * 64;                   // ct(8) x kc(nkc) x lane(64)
    if (gid >= total) return;
    int lane = gid & 63;
    int frag = gid >> 6;
    int kc = frag % nkc;
    int ct = frag / nkc;
    int col = ct * 16 + (lane & 15);
    int kbase = kc * 32 + (lane >> 4) * 8;
    size_t o = (size_t)gid * 8;
#pragma unroll
    for (int j = 0; j < 8; j++) {
        unsigned h, l;
        splitt(src[(size_t)(kbase + j) * 128 + col], h, l);
        dh[o + j] = (short)h;
        dl[o + j] = (short)l;
    }
}

// ---------------- CSR build (by rcvr) ----------------
__global__ void k_zero_i(int* p, int n) {
    int i = blockIdx.x * 256 + threadIdx.x;
    if (i < n) p[i] = 0;
}
__global__ void k_count(const int* __restrict__ rcvr, int* __restrict__ deg) {
    int e = blockIdx.x * 256 + threadIdx.x;
    if (e < NEc) atomicAdd(&deg[rcvr[e]], 1);
}
// 3-phase multi-block exclusive scan
__global__ void k_scan1(const int* __restrict__ deg, int* __restrict__ partial) {
    __shared__ int buf[256];
    int t = threadIdx.x;
    int i = blockIdx.x * 256 + t;
    buf[t] = (i < NNc) ? deg[i] : 0;
    __syncthreads();
    for (int off = 128; off > 0; off >>= 1) {
        if (t < off) buf[t] += buf[t + off];
        __syncthreads();
    }
    if (t == 0) partial[blockIdx.x] = buf[0];
}
__global__ void k_scan2(int* __restrict__ partial) {
    __shared__ int buf[256];
    int t = threadIdx.x;
    int v = (t < NSB) ? partial[t] : 0;
    buf[t] = v;
    __syncthreads();
    for (int off = 1; off < 256; off <<= 1) {
        int u = (t >= off) ? buf[t - off] : 0;
        __syncthreads();
        buf[t] += u;
        __syncthreads();
    }
    if (t < NSB) partial[t] = buf[t] - v;   // exclusive
}
__global__ void k_scan3(const int* __restrict__ deg, const int* __restrict__ partial,
                        int* __restrict__ rowstart, int* __restrict__ cursor) {
    __shared__ int buf[256];
    int t = threadIdx.x;
    int i = blockIdx.x * 256 + t;
    int v = (i < NNc) ? deg[i] : 0;
    buf[t] = v;
    __syncthreads();
    for (int off = 1; off < 256; off <<= 1) {
        int u = (t >= off) ? buf[t - off] : 0;
        __syncthreads();
        buf[t] += u;
        __syncthreads();
    }
    int excl = partial[blockIdx.x] + buf[t] - v;
    if (i < NNc) { rowstart[i] = excl; cursor[i] = excl; }
    if (i == NNc - 1) rowstart[NNc] = excl + v;
}
__global__ void k_scatter(const int* __restrict__ sndr, const int* __restrict__ rcvr,
                          int* __restrict__ cursor, int2* __restrict__ csr_se) {
    int e = blockIdx.x * 256 + threadIdx.x;
    if (e >= NEc) return;
    int rv = rcvr[e];
    int p = atomicAdd(&cursor[rv], 1);
    csr_se[p] = make_int2(sndr[e], e);
}

// ---------------- flows / elementwise ----------------
__global__ void k_qinit(const float* __restrict__ x, const float* __restrict__ r,
                        const int* __restrict__ sndr, const int* __restrict__ rcvr,
                        float* __restrict__ qh, float* __restrict__ qt) {
    int e = blockIdx.x * 256 + threadIdx.x;
    if (e >= NEc) return;
    float hv = x[2 * sndr[e]] - x[2 * rcvr[e]];
    float q = signf(hv) * __powf((fabsf(hv) + ZETAc) / (r[e] + ZETAc), INVPc);
    qh[e] = q; qt[e] = q;
}
__global__ void k_flows_q(const float* __restrict__ h, const float* __restrict__ r,
                          const int* __restrict__ sndr, const int* __restrict__ rcvr,
                          float* __restrict__ qt) {
    int e = blockIdx.x * 256 + threadIdx.x;
    if (e >= NEc) return;
    float hv = h[sndr[e]] - h[rcvr[e]];
    qt[e] = signf(hv) * __powf((fabsf(hv) + ZETAc) / (r[e] + ZETAc), INVPc);
}

// node-in, fused segsum: one WAVE per node. Produces split-selu g planes.
__global__ __launch_bounds__(256) void k_node_in_f(
    const float* __restrict__ qh, const int* __restrict__ rowstart,
    const int2* __restrict__ csr_se, const float* __restrict__ x,
    const float* __restrict__ W /*2x128*/,
    unsigned* __restrict__ gh_u, unsigned* __restrict__ gl_u) {
    const int tid = threadIdx.x;
    const int lane = tid & 63;
    const int n = rfl(blockIdx.x * 4 + (tid >> 6));
    if (n >= NNc) return;
    int p0 = rfl(rowstart[n]), p1 = rfl(rowstart[n + 1]);
    float s = 0.0f;
    for (int p = p0 + lane; p < p1; p += 64) s += qh[csr_se[p].y];
#pragma unroll
    for (int off = 1; off < 64; off <<= 1) s += __shfl_xor(s, off, 64);
    float s0 = selu_f(s);
    float s1 = selu_f(x[2 * n + 1]);
    int c = lane * 2;
    float g0 = s0 * W[c]     + s1 * W[MLc + c];
    float g1 = s0 * W[c + 1] + s1 * W[MLc + c + 1];
    unsigned h0, l0, h1, l1;
    splitt(selu_f(g0), h0, l0);
    splitt(selu_f(g1), h1, l1);
    gh_u[(size_t)n * 64 + lane] = h0 | (h1 << 16);
    gl_u[(size_t)n * 64 + lane] = l0 | (l1 << 16);
}

// one head-propagation iteration, CSR gather; hin has stride (2 for x, 1 for h buf)
__global__ __launch_bounds__(64) void k_head_iter(
    const float* __restrict__ x, const float* __restrict__ hin, int hstride,
    const float* __restrict__ hl, const int* __restrict__ rowstart,
    const int2* __restrict__ csr_se, float* __restrict__ hout) {
    int n = blockIdx.x * 64 + threadIdx.x;
    if (n >= NNc) return;
    float hv = hin[(size_t)n * hstride];
    float m = -3.0e38f;
    int p0 = rowstart[n], p1 = rowstart[n + 1];
    for (int p = p0; p < p1; p++) {
        int2 se = csr_se[p];
        m = fmaxf(m, hin[(size_t)se.x * hstride] - hl[se.y]);
    }
    float a = (m > -1e30f) ? m : hv;
    float hstar = x[2 * n];
    hout[n] = (hstar != 0.0f) ? hstar : fmaxf(hv, a);
}

// ---------------- split-bf16 MFMA MLP kernels ----------------
// 32-row tile, 512 threads = 8 waves; wave = 16-col tile x both 16-row tiles.
// Staging addresses scalarized via readfirstlane (s_load + SALU, saddr-form DMA).
// A-frag: row=lane&15, k=quad*8+j. C/D: col=lane&15, row=quad*4+reg.

#define MS_E 392   // 384+8 shorts
#define MS_N 264   // 256+8
#define TS   136   // 128+8

__global__ __launch_bounds__(512) void k_edge_mlp_mfma(
    const unsigned* __restrict__ gh_u, const unsigned* __restrict__ gl_u,
    const unsigned* __restrict__ zh_u, const unsigned* __restrict__ zl_u,
    short* __restrict__ zoh_s, short* __restrict__ zol_s,
    const short* __restrict__ W1h, const short* __restrict__ W1l,
    const short* __restrict__ W2h, const short* __restrict__ W2l,
    const int* __restrict__ sndr, const int* __restrict__ rcvr,
    const float* __restrict__ qt, const float* __restrict__ qh,
    const float* __restrict__ Wei, int zmode) {
    __shared__ short smem[2 * 32 * MS_E];        // 50176 B
    short* m_hi = smem;
    short* m_lo = smem + 32 * MS_E;
    short* t_hi = smem;                          // alias front (post-barrier)
    short* t_lo = smem + 32 * TS;
    const int tid = threadIdx.x;
    const int bi = blockIdx.x;
    const int x7 = bi & 7, jj = bi >> 3;
    const int e0 = ((x7 >> 1) * 1000 + (x7 & 1) * 500 + jj) * 32;   // XCD swizzle
    const int lane = tid & 63, wave = tid >> 6;

    if (zmode == 0) {
        for (int t = wave; t < 96; t += 8) {
            int row = t & 31, region = t >> 5;
            int e = rfl(e0 + row);
            size_t o;
            const unsigned *ph, *pl;
            if (region == 0)      { o = (size_t)rfl(sndr[e]) * 64; ph = gh_u; pl = gl_u; }
            else if (region == 1) { o = (size_t)rfl(rcvr[e]) * 64; ph = gh_u; pl = gl_u; }
            else                  { o = (size_t)e * 64;            ph = zh_u; pl = zl_u; }
            load_lds4(ph + o + lane, &m_hi[row * MS_E + region * 128]);
            load_lds4(pl + o + lane, &m_lo[row * MS_E + region * 128]);
        }
    } else {
        for (int t = wave; t < 64; t += 8) {
            int row = t & 31, region = t >> 5;
            int e = rfl(e0 + row);
            size_t o = (size_t)rfl(region == 0 ? sndr[e] : rcvr[e]) * 64;
            load_lds4(gh_u + o + lane, &m_hi[row * MS_E + region * 128]);
            load_lds4(gl_u + o + lane, &m_lo[row * MS_E + region * 128]);
        }
        for (int idx = tid; idx < 32 * 64; idx += 512) {
            int row = rfl(idx >> 6);          // wave-uniform each iteration
            int cp = idx & 63;
            int e = rfl(e0 + row);
            float sqt = selu_f(qt[e]), sqh = selu_f(qh[e]);
            int c = 2 * cp;
            float z0 = sqt * Wei[c]     + sqh * Wei[MLc + c];
            float z1 = sqt * Wei[c + 1] + sqh * Wei[MLc + c + 1];
            unsigned h0, l0, h1, l1;
            splitt(selu_f(z0), h0, l0);
            splitt(selu_f(z1), h1, l1);
            int k = 256 + 2 * cp;
            *(unsigned*)&m_hi[row * MS_E + k] = h0 | (h1 << 16);
            *(unsigned*)&m_lo[row * MS_E + k] = l0 | (l1 << 16);
        }
    }
    __syncthreads();

    const int ct = wave;
    const int l15 = lane & 15, quad = lane >> 4;
    const int col = ct * 16 + l15;

    f32x4 acc[2];
    acc[0] = (f32x4){0.f, 0.f, 0.f, 0.f};
    acc[1] = (f32x4){0.f, 0.f, 0.f, 0.f};
#pragma unroll 4
    for (int kc = 0; kc < 12; kc++) {
        size_t wo = ((size_t)(ct * 12 + kc) * 64 + lane) * 8;   // fragment-linear
        short8 bh = *(const short8*)&W1h[wo];
        short8 bl = *(const short8*)&W1l[wo];
#pragma unroll
        for (int rt = 0; rt < 2; rt++) {
            const short* ap = &m_hi[(rt * 16 + l15) * MS_E + kc * 32 + quad * 8];
            short8 ah = *(const short8*)ap;
            short8 al = *(const short8*)(ap + 32 * MS_E);
            acc[rt] = __builtin_amdgcn_mfma_f32_16x16x32_bf16(ah, bh, acc[rt], 0, 0, 0);
            acc[rt] = __builtin_amdgcn_mfma_f32_16x16x32_bf16(al, bh, acc[rt], 0, 0, 0);
            acc[rt] = __builtin_amdgcn_mfma_f32_16x16x32_bf16(ah, bl, acc[rt], 0, 0, 0);
        }
    }
    __syncthreads();
#pragma unroll
    for (int rt = 0; rt < 2; rt++) {
#pragma unroll
        for (int rr = 0; rr < 4; rr++) {
            unsigned h, l;
            splitt(selu_f(acc[rt][rr]), h, l);
            t_hi[(rt * 16 + quad * 4 + rr) * TS + col] = (short)h;
            t_lo[(rt * 16 + quad * 4 + rr) * TS + col] = (short)l;
        }
    }
    __syncthreads();

    f32x4 acc2[2];
    acc2[0] = (f32x4){0.f, 0.f, 0.f, 0.f};
    acc2[1] = (f32x4){0.f, 0.f, 0.f, 0.f};
#pragma unroll
    for (int kc = 0; kc < 4; kc++) {
        size_t wo = ((size_t)(ct * 4 + kc) * 64 + lane) * 8;
        short8 bh = *(const short8*)&W2h[wo];
        short8 bl = *(const short8*)&W2l[wo];
#pragma unroll
        for (int rt = 0; rt < 2; rt++) {
            const short* ap = &t_hi[(rt * 16 + l15) * TS + kc * 32 + quad * 8];
            short8 ah = *(const short8*)ap;
            short8 al = *(const short8*)(ap + 32 * TS);
            acc2[rt] = __builtin_amdgcn_mfma_f32_16x16x32_bf16(ah, bh, acc2[rt], 0, 0, 0);
            acc2[rt] = __builtin_amdgcn_mfma_f32_16x16x32_bf16(al, bh, acc2[rt], 0, 0, 0);
            acc2[rt] = __builtin_amdgcn_mfma_f32_16x16x32_bf16(ah, bl, acc2[rt], 0, 0, 0);
        }
    }
#pragma unroll
    for (int rt = 0; rt < 2; rt++) {
#pragma unroll
        for (int rr = 0; rr < 4; rr++) {
            unsigned h, l;
            splitt(selu_f(acc2[rt][rr]), h, l);
            size_t o = (size_t)(e0 + rt * 16 + quad * 4 + rr) * 128 + col;
            zoh_s[o] = (short)h;
            zol_s[o] = (short)l;
        }
    }
}

// node MLP: g-gather via global_load_lds + selu-space segment max of z planes
__global__ __launch_bounds__(512) void k_node_mlp_mfma(
    const unsigned* __restrict__ gh_u, const unsigned* __restrict__ gl_u,
    short* __restrict__ goh_s, short* __restrict__ gol_s,
    const unsigned* __restrict__ zh_u, const unsigned* __restrict__ zl_u,
    const int* __restrict__ rowstart, const int2* __restrict__ csr_se,
    const short* __restrict__ W1h, const short* __restrict__ W1l,
    const short* __restrict__ W2h, const short* __restrict__ W2l) {
    __shared__ short smem[2 * 32 * MS_N];        // 33792 B
    short* m_hi = smem;
    short* m_lo = smem + 32 * MS_N;
    short* t_hi = smem;
    short* t_lo = smem + 32 * TS;
    const int tid = threadIdx.x;
    const int n0 = blockIdx.x * 32;
    const int lane = tid & 63, wave = tid >> 6;

    for (int t = wave; t < 32; t += 8) {
        int n = rfl(n0 + t);
        load_lds4(gh_u + (size_t)n * 64 + lane, &m_hi[t * MS_N]);
        load_lds4(gl_u + (size_t)n * 64 + lane, &m_lo[t * MS_N]);
    }
    for (int idx = tid; idx < 32 * 64; idx += 512) {
        int row = rfl(idx >> 6);              // wave-uniform each iteration
        int cp = idx & 63;
        int n = rfl(n0 + row);
        int p0 = rfl(rowstart[n]), p1 = rfl(rowstart[n + 1]);
        float b0 = -3.0e38f, b1 = -3.0e38f;
        unsigned bh0 = 0, bl0 = 0, bh1 = 0, bl1 = 0;  // default split(0)
        for (int p = p0; p < p1; p++) {
            int ey = rfl(csr_se[p].y);        // scalar edge index
            size_t o = (size_t)ey * 64 + cp;
            unsigned vh = zh_u[o], vl = zl_u[o];
            float f0 = __uint_as_float(vh << 16) + __uint_as_float(vl << 16);
            float f1 = __uint_as_float(vh & 0xffff0000u) + __uint_as_float(vl & 0xffff0000u);
            if (f0 > b0) { b0 = f0; bh0 = vh & 0xffffu; bl0 = vl & 0xffffu; }
            if (f1 > b1) { b1 = f1; bh1 = vh & 0xffff0000u; bl1 = vl & 0xffff0000u; }
        }
        int k = 128 + 2 * cp;
        *(unsigned*)&m_hi[row * MS_N + k] = bh0 | bh1;
        *(unsigned*)&m_lo[row * MS_N + k] = bl0 | bl1;
    }
    __syncthreads();

    const int ct = wave;
    const int l15 = lane & 15, quad = lane >> 4;
    const int col = ct * 16 + l15;

    f32x4 acc[2];
    acc[0] = (f32x4){0.f, 0.f, 0.f, 0.f};
    acc[1] = (f32x4){0.f, 0.f, 0.f, 0.f};
#pragma unroll 4
    for (int kc = 0; kc < 8; kc++) {
        size_t wo = ((size_t)(ct * 8 + kc) * 64 + lane) * 8;
        short8 bh = *(const short8*)&W1h[wo];
        short8 bl = *(const short8*)&W1l[wo];
#pragma unroll
        for (int rt = 0; rt < 2; rt++) {
            const short* ap = &m_hi[(rt * 16 + l15) * MS_N + kc * 32 + quad * 8];
            short8 ah = *(const short8*)ap;
            short8 al = *(const short8*)(ap + 32 * MS_N);
            acc[rt] = __builtin_amdgcn_mfma_f32_16x16x32_bf16(ah, bh, acc[rt], 0, 0, 0);
            acc[rt] = __builtin_amdgcn_mfma_f32_16x16x32_bf16(al, bh, acc[rt], 0, 0, 0);
            acc[rt] = __builtin_amdgcn_mfma_f32_16x16x32_bf16(ah, bl, acc[rt], 0, 0, 0);
        }
    }
    __syncthreads();
#pragma unroll
    for (int rt = 0; rt < 2; rt++) {
#pragma unroll
        for (int rr = 0; rr < 4; rr++) {
            unsigned h, l;
            splitt(selu_f(acc[rt][rr]), h, l);
            t_hi[(rt * 16 + quad * 4 + rr) * TS + col] = (short)h;
            t_lo[(rt * 16 + quad * 4 + rr) * TS + col] = (short)l;
        }
    }
    __syncthreads();

    f32x4 acc2[2];
    acc2[0] = (f32x4){0.f, 0.f, 0.f, 0.f};
    acc2[1] = (f32x4){0.f, 0.f, 0.f, 0.f};
#pragma unroll
    for (int kc = 0; kc < 4; kc++) {
        size_t wo = ((size_t)(ct * 4 + kc) * 64 + lane) * 8;
        short8 bh = *(const short8*)&W2h[wo];
        short8 bl = *(const short8*)&W2l[wo];
#pragma unroll
        for (int rt = 0; rt < 2; rt++) {
            const short* ap = &t_hi[(rt * 16 + l15) * TS + kc * 32 + quad * 8];
            short8 ah = *(const short8*)ap;
            short8 al = *(const short8*)(ap + 32 * TS);
            acc2[rt] = __builtin_amdgcn_mfma_f32_16x16x32_bf16(ah, bh, acc2[rt], 0, 0, 0);
            acc2[rt] = __builtin_amdgcn_mfma_f32_16x16x32_bf16(al, bh, acc2[rt], 0, 0, 0);
            acc2[rt] = __builtin_amdgcn_mfma_f32_16x16x32_bf16(ah, bl, acc2[rt], 0, 0, 0);
        }
    }
#pragma unroll
    for (int rt = 0; rt < 2; rt++) {
#pragma unroll
        for (int rr = 0; rr < 4; rr++) {
            unsigned h, l;
            splitt(selu_f(acc2[rt][rr]), h, l);
            size_t o = (size_t)(n0 + rt * 16 + quad * 4 + rr) * 128 + col;
            goh_s[o] = (short)h;
            gol_s[o] = (short)l;
        }
    }
}

// Wf chain on first-half edges: q_new = q_old + selu(selu(lam@Wf1)@Wf2)@Wf3;
// antisymmetrize; ALSO computes hl for both halves (hl[e+E2] = -hl[e]).
__global__ __launch_bounds__(512) void k_wf_mfma(
    const unsigned* __restrict__ gh_u, const unsigned* __restrict__ gl_u,
    const unsigned* __restrict__ zh_u, const unsigned* __restrict__ zl_u,
    const short* __restrict__ W1h, const short* __restrict__ W1l,
    const short* __restrict__ W2h, const short* __restrict__ W2l,
    const float* __restrict__ W3 /*[128]*/,
    const int* __restrict__ sndr, const int* __restrict__ rcvr,
    const float* __restrict__ r,
    float* __restrict__ qh, float* __restrict__ hl) {
    __shared__ short smem[2 * 32 * MS_E];
    __shared__ float red[32 * 8];
    short* m_hi = smem;
    short* m_lo = smem + 32 * MS_E;
    short* t_hi = smem;
    short* t_lo = smem + 32 * TS;
    const int tid = threadIdx.x;
    const int bi = blockIdx.x;
    const int x7 = bi & 7, jj = bi >> 3;
    const int fi0 = ((x7 >> 1) * 500 + (x7 & 1) * 250 + jj) * 32;
    const int b = fi0 / E2c;
    const int ebase = b * EPGc - b * E2c;     // e = ebase + fi
    const int lane = tid & 63, wave = tid >> 6;

    for (int t = wave; t < 96; t += 8) {
        int row = t & 31, region = t >> 5;
        int e = rfl(ebase + fi0 + row);
        size_t o;
        const unsigned *ph, *pl;
        if (region == 0)      { o = (size_t)rfl(sndr[e]) * 64; ph = gh_u; pl = gl_u; }
        else if (region == 1) { o = (size_t)rfl(rcvr[e]) * 64; ph = gh_u; pl = gl_u; }
        else                  { o = (size_t)e * 64;            ph = zh_u; pl = zl_u; }
        load_lds4(ph + o + lane, &m_hi[row * MS_E + region * 128]);
        load_lds4(pl + o + lane, &m_lo[row * MS_E + region * 128]);
    }
    __syncthreads();

    const int ct = wave;
    const int l15 = lane & 15, quad = lane >> 4;
    const int col = ct * 16 + l15;

    f32x4 acc[2];
    acc[0] = (f32x4){0.f, 0.f, 0.f, 0.f};
    acc[1] = (f32x4){0.f, 0.f, 0.f, 0.f};
#pragma unroll 4
    for (int kc = 0; kc < 12; kc++) {
        size_t wo = ((size_t)(ct * 12 + kc) * 64 + lane) * 8;
        short8 bh = *(const short8*)&W1h[wo];
        short8 bl = *(const short8*)&W1l[wo];
#pragma unroll
        for (int rt = 0; rt < 2; rt++) {
            const short* ap = &m_hi[(rt * 16 + l15) * MS_E + kc * 32 + quad * 8];
            short8 ah = *(const short8*)ap;
            short8 al = *(const short8*)(ap + 32 * MS_E);
            acc[rt] = __builtin_amdgcn_mfma_f32_16x16x32_bf16(ah, bh, acc[rt], 0, 0, 0);
            acc[rt] = __builtin_amdgcn_mfma_f32_16x16x32_bf16(al, bh, acc[rt], 0, 0, 0);
            acc[rt] = __builtin_amdgcn_mfma_f32_16x16x32_bf16(ah, bl, acc[rt], 0, 0, 0);
        }
    }
    __syncthreads();
#pragma unroll
    for (int rt = 0; rt < 2; rt++) {
#pragma unroll
        for (int rr = 0; rr < 4; rr++) {
            unsigned h, l;
            splitt(selu_f(acc[rt][rr]), h, l);
            t_hi[(rt * 16 + quad * 4 + rr) * TS + col] = (short)h;
            t_lo[(rt * 16 + quad * 4 + rr) * TS + col] = (short)l;
        }
    }
    __syncthreads();

    f32x4 acc2[2];
    acc2[0] = (f32x4){0.f, 0.f, 0.f, 0.f};
    acc2[1] = (f32x4){0.f, 0.f, 0.f, 0.f};
#pragma unroll
    for (int kc = 0; kc < 4; kc++) {
        size_t wo = ((size_t)(ct * 4 + kc) * 64 + lane) * 8;
        short8 bh = *(const short8*)&W2h[wo];
        short8 bl = *(const short8*)&W2l[wo];
#pragma unroll
        for (int rt = 0; rt < 2; rt++) {
            const short* ap = &t_hi[(rt * 16 + l15) * TS + kc * 32 + quad * 8];
            short8 ah = *(const short8*)ap;
            short8 al = *(const short8*)(ap + 32 * TS);
            acc2[rt] = __builtin_amdgcn_mfma_f32_16x16x32_bf16(ah, bh, acc2[rt], 0, 0, 0);
            acc2[rt] = __builtin_amdgcn_mfma_f32_16x16x32_bf16(al, bh, acc2[rt], 0, 0, 0);
            acc2[rt] = __builtin_amdgcn_mfma_f32_16x16x32_bf16(ah, bl, acc2[rt], 0, 0, 0);
        }
    }
    float w3 = W3[col];
    float p[8];
#pragma unroll
    for (int rt = 0; rt < 2; rt++)
#pragma unroll
        for (int rr = 0; rr < 4; rr++) p[rt * 4 + rr] = selu_f(acc2[rt][rr]) * w3;
#pragma unroll
    for (int off = 1; off < 16; off <<= 1) {
#pragma unroll
        for (int i = 0; i < 8; i++) p[i] += __shfl_xor(p[i], off, 64);
    }
    if (l15 == 0) {
#pragma unroll
        for (int rt = 0; rt < 2; rt++)
#pragma unroll
            for (int rr = 0; rr < 4; rr++)
                red[(rt * 16 + quad * 4 + rr) * 8 + ct] = p[rt * 4 + rr];
    }
    __syncthreads();
    if (tid < 32) {
        float f = 0.0f;
#pragma unroll
        for (int c = 0; c < 8; c++) f += red[tid * 8 + c];
        int e = ebase + fi0 + tid;
        float qn = qh[e] + f;
        qh[e] = qn;
        qh[e + E2c] = -qn;
        float hv = r[e] * signf(qn) * __powf(fabsf(qn), PEXPc);
        hl[e] = hv;
        hl[e + E2c] = -hv;
    }
}

// ---------------- host orchestration ----------------

extern "C" void kernel_launch(void* const* d_in, const int* in_sizes, int n_in,
                              void* d_out, int out_size, void* d_ws, size_t ws_size,
                              hipStream_t stream) {
    const float* x   = (const float*)d_in[0];
    const float* r   = (const float*)d_in[1];
    const float* Wni = (const float*)d_in[2];
    const float* Wei = (const float*)d_in[3];
    const float* Wf1 = (const float*)d_in[4];
    const float* Wf2 = (const float*)d_in[5];
    const float* Wf3 = (const float*)d_in[6];
    const float* We1 = (const float*)d_in[7];   // (3,384,128)
    const float* We2 = (const float*)d_in[8];   // (3,128,128)
    const float* Wn1 = (const float*)d_in[9];   // (3,256,128)
    const float* Wn2 = (const float*)d_in[10];  // (3,128,128)
    const int* sndr  = (const int*)d_in[11];
    const int* rcvr  = (const int*)d_in[12];
    float* out = (float*)d_out;

    char* wp = (char*)d_ws;
    auto carve = [&](size_t bytes) -> void* {
        void* ret = (void*)wp;
        wp += (bytes + 255) & ~(size_t)255;
        return ret;
    };
    unsigned* gh_u = (unsigned*)carve((size_t)NNc * 64 * 4);
    unsigned* gl_u = (unsigned*)carve((size_t)NNc * 64 * 4);
    unsigned* zAh  = (unsigned*)carve((size_t)NEc * 64 * 4);
    unsigned* zAl  = (unsigned*)carve((size_t)NEc * 64 * 4);
    unsigned* zBh  = (unsigned*)carve((size_t)NEc * 64 * 4);
    unsigned* zBl  = (unsigned*)carve((size_t)NEc * 64 * 4);
    float* qh     = (float*)carve((size_t)NEc * 4);
    float* qt     = (float*)carve((size_t)NEc * 4);
    float* hl     = (float*)carve((size_t)NEc * 4);
    float* hA     = (float*)carve((size_t)NNc * 4);
    float* hB     = (float*)carve((size_t)NNc * 4);
    int*   deg    = (int*)carve((size_t)NNc * 4);
    int*   cursor = (int*)carve((size_t)NNc * 4);
    int*   rowst  = (int*)carve((size_t)(NNc + 1) * 4);
    int*   part   = (int*)carve((size_t)NSB * 4);
    int2*  csr_se = (int2*)carve((size_t)NEc * 8);
    short* we1h   = (short*)carve((size_t)3 * 128 * 384 * 2);
    short* we1l   = (short*)carve((size_t)3 * 128 * 384 * 2);
    short* we2h   = (short*)carve((size_t)3 * 128 * 128 * 2);
    short* we2l   = (short*)carve((size_t)3 * 128 * 128 * 2);
    short* wn1h   = (short*)carve((size_t)3 * 128 * 256 * 2);
    short* wn1l   = (short*)carve((size_t)3 * 128 * 256 * 2);
    short* wn2h   = (short*)carve((size_t)3 * 128 * 128 * 2);
    short* wn2l   = (short*)carve((size_t)3 * 128 * 128 * 2);
    short* wf1h   = (short*)carve((size_t)128 * 384 * 2);
    short* wf1l   = (short*)carve((size_t)128 * 384 * 2);
    short* wf2h   = (short*)carve((size_t)128 * 128 * 2);
    short* wf2l   = (short*)carve((size_t)128 * 128 * 2);

    const int TB = 256;
    const int gN  = (NNc + TB - 1) / TB;
    const int gE  = (NEc + TB - 1) / TB;

    // fragment-linear weight planes (nkc = K/32)
    for (int i = 0; i < 3; i++) {
        k_wconv_frag<<<(8 * 12 * 64 + 255) / 256, TB, 0, stream>>>(We1 + (size_t)i * 384 * 128, we1h + (size_t)i * 128 * 384, we1l + (size_t)i * 128 * 384, 12);
        k_wconv_frag<<<(8 * 4 * 64 + 255) / 256, TB, 0, stream>>>(We2 + (size_t)i * 128 * 128, we2h + (size_t)i * 128 * 128, we2l + (size_t)i * 128 * 128, 4);
        k_wconv_frag<<<(8 * 8 * 64 + 255) / 256, TB, 0, stream>>>(Wn1 + (size_t)i * 256 * 128, wn1h + (size_t)i * 128 * 256, wn1l + (size_t)i * 128 * 256, 8);
        k_wconv_frag<<<(8 * 4 * 64 + 255) / 256, TB, 0, stream>>>(Wn2 + (size_t)i * 128 * 128, wn2h + (size_t)i * 128 * 128, wn2l + (size_t)i * 128 * 128, 4);
    }
    k_wconv_frag<<<(8 * 12 * 64 + 255) / 256, TB, 0, stream>>>(Wf1, wf1h, wf1l, 12);
    k_wconv_frag<<<(8 * 4 * 64 + 255) / 256, TB, 0, stream>>>(Wf2, wf2h, wf2l, 4);

    // CSR build (multi-block scan)
    k_zero_i<<<gN, TB, 0, stream>>>(deg, NNc);
    k_count<<<gE, TB, 0, stream>>>(rcvr, deg);
    k_scan1<<<NSB, TB, 0, stream>>>(deg, part);
    k_scan2<<<1, TB, 0, stream>>>(part);
    k_scan3<<<NSB, TB, 0, stream>>>(deg, part, rowst, cursor);
    k_scatter<<<gE, TB, 0, stream>>>(sndr, rcvr, cursor, csr_se);

    // initial flows
    k_qinit<<<gE, TB, 0, stream>>>(x, r, sndr, rcvr, qh, qt);

    const int gH = (NNc + 63) / 64;
    for (int kit = 0; kit < 4; kit++) {
        k_node_in_f<<<(NNc + 3) / 4, TB, 0, stream>>>(qh, rowst, csr_se, x, Wni, gh_u, gl_u);
        unsigned *zin_h = zAh, *zin_l = zAl, *zout_h = zAh, *zout_l = zAl;
        for (int i = 0; i < 3; i++) {
            zin_h = zout_h; zin_l = zout_l;
            zout_h = (i & 1) ? zAh : zBh;
            zout_l = (i & 1) ? zAl : zBl;
            k_edge_mlp_mfma<<<NEc / 32, 512, 0, stream>>>(
                gh_u, gl_u, zin_h, zin_l, (short*)zout_h, (short*)zout_l,
                we1h + (size_t)i * 128 * 384, we1l + (size_t)i * 128 * 384,
                we2h + (size_t)i * 128 * 128, we2l + (size_t)i * 128 * 128,
                sndr, rcvr, qt, qh, Wei, (i == 0) ? 1 : 0);
            k_node_mlp_mfma<<<NNc / 32, 512, 0, stream>>>(
                gh_u, gl_u, (short*)gh_u, (short*)gl_u, zout_h, zout_l, rowst, csr_se,
                wn1h + (size_t)i * 128 * 256, wn1l + (size_t)i * 128 * 256,
                wn2h + (size_t)i * 128 * 128, wn2l + (size_t)i * 128 * 128);
        }
        k_wf_mfma<<<(4 * E2c) / 32, 512, 0, stream>>>(
            gh_u, gl_u, zout_h, zout_l, wf1h, wf1l, wf2h, wf2l, Wf3, sndr, rcvr,
            r, qh, hl);
        // head propagation: 6 iterations; first reads h_star straight from x (stride 2)
        const float* hin = x; int hstride = 2;
        float* cur = hA;
        for (int jh = 0; jh < 6; jh++) {
            float* dst = (jh == 5) ? ((kit == 3) ? out : hB) : cur;
            k_head_iter<<<gH, 64, 0, stream>>>(x, hin, hstride, hl, rowst, csr_se, dst);
            hin = dst; hstride = 1;
            cur = (dst == hA) ? hB : hA;
        }
        if (kit < 3) k_flows_q<<<gE, TB, 0, stream>>>(hB, r, sndr, rcvr, qt);
    }
}

// Round 14
// 1896.891 us; speedup vs baseline: 1.6465x; 1.0019x over previous
//
#include <hip/hip_runtime.h>
#include <hip/hip_bf16.h>
#include <math.h>

// Problem constants
#define NPGc  10000
#define EPGc  32000
#define MLc   128
#define NNc   40000      // N
#define NEc   128000     // E
#define E2c   16000      // EPG/2
#define ZETAc 1e-6f
#define INVPc 0.53995680345572354f   // 1/1.852
#define PEXPc 1.852f
#define NSB   ((NNc + 255) / 256)    // 157 scan blocks

typedef __attribute__((ext_vector_type(8))) short short8;   // 8 bf16 (4 VGPRs)
typedef __attribute__((ext_vector_type(4))) float f32x4;    // MFMA acc

// fast selu: __expf -> v_exp_f32
__device__ __forceinline__ float selu_f(float x) {
    float e = __expf(x) - 1.0f;
    return 1.0507009873554805f * (x > 0.0f ? x : 1.6732632423543772f * e);
}
// cheap split fp32 -> (hi, lo): hi = truncated top-16 bits (exact rem), lo = RNE(rem).
__device__ __forceinline__ void splitt(float v, unsigned& hi, unsigned& lo) {
    unsigned u = __float_as_uint(v);
    hi = u >> 16;
    float rem = v - __uint_as_float(u & 0xffff0000u);
    __hip_bfloat16 l = __float2bfloat16(rem);
    lo = (unsigned short)*reinterpret_cast<short*>(&l);
}
__device__ __forceinline__ float signf(float x) {
    return (x > 0.0f) ? 1.0f : (x < 0.0f ? -1.0f : 0.0f);
}
__device__ __forceinline__ int rfl(int v) { return __builtin_amdgcn_readfirstlane(v); }

// async global->LDS: 64 lanes x 4B, wave-uniform LDS base + lane*4
__device__ __forceinline__ void load_lds4(const unsigned* src, short* dst) {
    __builtin_amdgcn_global_load_lds(
        (const __attribute__((address_space(1))) unsigned*)src,
        (__attribute__((address_space(3))) unsigned*)dst, 4, 0, 0);
}

// ---------------- weight convert+split into MFMA B-FRAGMENT-LINEAR layout ------------
// B-frag for mfma_16x16x32: n = ct*16 + (lane&15), k = kc*32 + (lane>>4)*8 + j.
__global__ void k_wconv_frag(const float* __restrict__ src, short* __restrict__ dh,
                             short* __restrict__ dl, int nkc /* = K/32 */) {
    int gid = blockIdx.x * 256 + threadIdx.x;   // one thread per (frag, lane)
    int total = 8 * nkc * 64;                   // ct(8) x kc(nkc) x lane(64)
    if (gid >= total) return;
    int lane = gid & 63;
    int frag = gid >> 6;
    int kc = frag % nkc;
    int ct = frag / nkc;
    int col = ct * 16 + (lane & 15);
    int kbase = kc * 32 + (lane >> 4) * 8;
    size_t o = (size_t)gid * 8;
#pragma unroll
    for (int j = 0; j < 8; j++) {
        unsigned h, l;
        splitt(src[(size_t)(kbase + j) * 128 + col], h, l);
        dh[o + j] = (short)h;
        dl[o + j] = (short)l;
    }
}

// ---------------- CSR build (by rcvr) ----------------
__global__ void k_zero_i(int* p, int n) {
    int i = blockIdx.x * 256 + threadIdx.x;
    if (i < n) p[i] = 0;
}
__global__ void k_count(const int* __restrict__ rcvr, int* __restrict__ deg) {
    int e = blockIdx.x * 256 + threadIdx.x;
    if (e < NEc) atomicAdd(&deg[rcvr[e]], 1);
}
// 3-phase multi-block exclusive scan
__global__ void k_scan1(const int* __restrict__ deg, int* __restrict__ partial) {
    __shared__ int buf[256];
    int t = threadIdx.x;
    int i = blockIdx.x * 256 + t;
    buf[t] = (i < NNc) ? deg[i] : 0;
    __syncthreads();
    for (int off = 128; off > 0; off >>= 1) {
        if (t < off) buf[t] += buf[t + off];
        __syncthreads();
    }
    if (t == 0) partial[blockIdx.x] = buf[0];
}
__global__ void k_scan2(int* __restrict__ partial) {
    __shared__ int buf[256];
    int t = threadIdx.x;
    int v = (t < NSB) ? partial[t] : 0;
    buf[t] = v;
    __syncthreads();
    for (int off = 1; off < 256; off <<= 1) {
        int u = (t >= off) ? buf[t - off] : 0;
        __syncthreads();
        buf[t] += u;
        __syncthreads();
    }
    if (t < NSB) partial[t] = buf[t] - v;   // exclusive
}
__global__ void k_scan3(const int* __restrict__ deg, const int* __restrict__ partial,
                        int* __restrict__ rowstart, int* __restrict__ cursor) {
    __shared__ int buf[256];
    int t = threadIdx.x;
    int i = blockIdx.x * 256 + t;
    int v = (i < NNc) ? deg[i] : 0;
    buf[t] = v;
    __syncthreads();
    for (int off = 1; off < 256; off <<= 1) {
        int u = (t >= off) ? buf[t - off] : 0;
        __syncthreads();
        buf[t] += u;
        __syncthreads();
    }
    int excl = partial[blockIdx.x] + buf[t] - v;
    if (i < NNc) { rowstart[i] = excl; cursor[i] = excl; }
    if (i == NNc - 1) rowstart[NNc] = excl + v;
}
__global__ void k_scatter(const int* __restrict__ sndr, const int* __restrict__ rcvr,
                          int* __restrict__ cursor, int2* __restrict__ csr_se) {
    int e = blockIdx.x * 256 + threadIdx.x;
    if (e >= NEc) return;
    int rv = rcvr[e];
    int p = atomicAdd(&cursor[rv], 1);
    csr_se[p] = make_int2(sndr[e], e);
}

// ---------------- flows / elementwise ----------------
__global__ void k_qinit(const float* __restrict__ x, const float* __restrict__ r,
                        const int* __restrict__ sndr, const int* __restrict__ rcvr,
                        float* __restrict__ qh, float* __restrict__ qt) {
    int e = blockIdx.x * 256 + threadIdx.x;
    if (e >= NEc) return;
    float hv = x[2 * sndr[e]] - x[2 * rcvr[e]];
    float q = signf(hv) * __powf((fabsf(hv) + ZETAc) / (r[e] + ZETAc), INVPc);
    qh[e] = q; qt[e] = q;
}
__global__ void k_flows_q(const float* __restrict__ h, const float* __restrict__ r,
                          const int* __restrict__ sndr, const int* __restrict__ rcvr,
                          float* __restrict__ qt) {
    int e = blockIdx.x * 256 + threadIdx.x;
    if (e >= NEc) return;
    float hv = h[sndr[e]] - h[rcvr[e]];
    qt[e] = signf(hv) * __powf((fabsf(hv) + ZETAc) / (r[e] + ZETAc), INVPc);
}

// node-in, fused segsum: one WAVE per node. Produces split-selu g planes.
__global__ __launch_bounds__(256) void k_node_in_f(
    const float* __restrict__ qh, const int* __restrict__ rowstart,
    const int2* __restrict__ csr_se, const float* __restrict__ x,
    const float* __restrict__ W /*2x128*/,
    unsigned* __restrict__ gh_u, unsigned* __restrict__ gl_u) {
    const int tid = threadIdx.x;
    const int lane = tid & 63;
    const int n = rfl(blockIdx.x * 4 + (tid >> 6));
    if (n >= NNc) return;
    int p0 = rfl(rowstart[n]), p1 = rfl(rowstart[n + 1]);
    float s = 0.0f;
    for (int p = p0 + lane; p < p1; p += 64) s += qh[csr_se[p].y];
#pragma unroll
    for (int off = 1; off < 64; off <<= 1) s += __shfl_xor(s, off, 64);
    float s0 = selu_f(s);
    float s1 = selu_f(x[2 * n + 1]);
    int c = lane * 2;
    float g0 = s0 * W[c]     + s1 * W[MLc + c];
    float g1 = s0 * W[c + 1] + s1 * W[MLc + c + 1];
    unsigned h0, l0, h1, l1;
    splitt(selu_f(g0), h0, l0);
    splitt(selu_f(g1), h1, l1);
    gh_u[(size_t)n * 64 + lane] = h0 | (h1 << 16);
    gl_u[(size_t)n * 64 + lane] = l0 | (l1 << 16);
}

// one head-propagation iteration, CSR gather; hin has stride (2 for x, 1 for h buf)
__global__ __launch_bounds__(64) void k_head_iter(
    const float* __restrict__ x, const float* __restrict__ hin, int hstride,
    const float* __restrict__ hl, const int* __restrict__ rowstart,
    const int2* __restrict__ csr_se, float* __restrict__ hout) {
    int n = blockIdx.x * 64 + threadIdx.x;
    if (n >= NNc) return;
    float hv = hin[(size_t)n * hstride];
    float m = -3.0e38f;
    int p0 = rowstart[n], p1 = rowstart[n + 1];
    for (int p = p0; p < p1; p++) {
        int2 se = csr_se[p];
        m = fmaxf(m, hin[(size_t)se.x * hstride] - hl[se.y]);
    }
    float a = (m > -1e30f) ? m : hv;
    float hstar = x[2 * n];
    hout[n] = (hstar != 0.0f) ? hstar : fmaxf(hv, a);
}

// ---------------- split-bf16 MFMA MLP kernels ----------------
// 32-row tile, 512 threads = 8 waves; wave = 16-col tile x both 16-row tiles.
// Staging addresses scalarized via readfirstlane (s_load + SALU, saddr-form DMA).
// A-frag: row=lane&15, k=quad*8+j. C/D: col=lane&15, row=quad*4+reg.

#define MS_E 392   // 384+8 shorts
#define MS_N 264   // 256+8
#define TS   136   // 128+8

__global__ __launch_bounds__(512) void k_edge_mlp_mfma(
    const unsigned* __restrict__ gh_u, const unsigned* __restrict__ gl_u,
    const unsigned* __restrict__ zh_u, const unsigned* __restrict__ zl_u,
    short* __restrict__ zoh_s, short* __restrict__ zol_s,
    const short* __restrict__ W1h, const short* __restrict__ W1l,
    const short* __restrict__ W2h, const short* __restrict__ W2l,
    const int* __restrict__ sndr, const int* __restrict__ rcvr,
    const float* __restrict__ qt, const float* __restrict__ qh,
    const float* __restrict__ Wei, int zmode) {
    __shared__ short smem[2 * 32 * MS_E];        // 50176 B
    short* m_hi = smem;
    short* m_lo = smem + 32 * MS_E;
    short* t_hi = smem;                          // alias front (post-barrier)
    short* t_lo = smem + 32 * TS;
    const int tid = threadIdx.x;
    const int bi = blockIdx.x;
    const int x7 = bi & 7, jj = bi >> 3;
    const int e0 = ((x7 >> 1) * 1000 + (x7 & 1) * 500 + jj) * 32;   // XCD swizzle
    const int lane = tid & 63, wave = tid >> 6;

    if (zmode == 0) {
        for (int t = wave; t < 96; t += 8) {
            int row = t & 31, region = t >> 5;
            int e = rfl(e0 + row);
            size_t o;
            const unsigned *ph, *pl;
            if (region == 0)      { o = (size_t)rfl(sndr[e]) * 64; ph = gh_u; pl = gl_u; }
            else if (region == 1) { o = (size_t)rfl(rcvr[e]) * 64; ph = gh_u; pl = gl_u; }
            else                  { o = (size_t)e * 64;            ph = zh_u; pl = zl_u; }
            load_lds4(ph + o + lane, &m_hi[row * MS_E + region * 128]);
            load_lds4(pl + o + lane, &m_lo[row * MS_E + region * 128]);
        }
    } else {
        for (int t = wave; t < 64; t += 8) {
            int row = t & 31, region = t >> 5;
            int e = rfl(e0 + row);
            size_t o = (size_t)rfl(region == 0 ? sndr[e] : rcvr[e]) * 64;
            load_lds4(gh_u + o + lane, &m_hi[row * MS_E + region * 128]);
            load_lds4(gl_u + o + lane, &m_lo[row * MS_E + region * 128]);
        }
        // one row per 16-thread slice: selu(qt/qh) computed ONCE per thread
        {
            int row = tid >> 4;            // 32 rows x 16 threads
            int sub = tid & 15;            // 8 col-pairs each
            int e = e0 + row;
            float sqt = selu_f(qt[e]), sqh = selu_f(qh[e]);
#pragma unroll
            for (int jcp = 0; jcp < 4; jcp++) {
                int cp = sub * 4 + jcp;
                int c = 2 * cp;
                float z0 = sqt * Wei[c]     + sqh * Wei[MLc + c];
                float z1 = sqt * Wei[c + 1] + sqh * Wei[MLc + c + 1];
                unsigned h0, l0, h1, l1;
                splitt(selu_f(z0), h0, l0);
                splitt(selu_f(z1), h1, l1);
                int k = 256 + 2 * cp;
                *(unsigned*)&m_hi[row * MS_E + k] = h0 | (h1 << 16);
                *(unsigned*)&m_lo[row * MS_E + k] = l0 | (l1 << 16);
            }
        }
    }
    __syncthreads();

    const int ct = wave;
    const int l15 = lane & 15, quad = lane >> 4;
    const int col = ct * 16 + l15;

    f32x4 acc[2];
    acc[0] = (f32x4){0.f, 0.f, 0.f, 0.f};
    acc[1] = (f32x4){0.f, 0.f, 0.f, 0.f};
#pragma unroll 4
    for (int kc = 0; kc < 12; kc++) {
        size_t wo = ((size_t)(ct * 12 + kc) * 64 + lane) * 8;   // fragment-linear
        short8 bh = *(const short8*)&W1h[wo];
        short8 bl = *(const short8*)&W1l[wo];
#pragma unroll
        for (int rt = 0; rt < 2; rt++) {
            const short* ap = &m_hi[(rt * 16 + l15) * MS_E + kc * 32 + quad * 8];
            short8 ah = *(const short8*)ap;
            short8 al = *(const short8*)(ap + 32 * MS_E);
            acc[rt] = __builtin_amdgcn_mfma_f32_16x16x32_bf16(ah, bh, acc[rt], 0, 0, 0);
            acc[rt] = __builtin_amdgcn_mfma_f32_16x16x32_bf16(al, bh, acc[rt], 0, 0, 0);
            acc[rt] = __builtin_amdgcn_mfma_f32_16x16x32_bf16(ah, bl, acc[rt], 0, 0, 0);
        }
    }
    __syncthreads();
#pragma unroll
    for (int rt = 0; rt < 2; rt++) {
#pragma unroll
        for (int rr = 0; rr < 4; rr++) {
            unsigned h, l;
            splitt(selu_f(acc[rt][rr]), h, l);
            t_hi[(rt * 16 + quad * 4 + rr) * TS + col] = (short)h;
            t_lo[(rt * 16 + quad * 4 + rr) * TS + col] = (short)l;
        }
    }
    __syncthreads();

    f32x4 acc2[2];
    acc2[0] = (f32x4){0.f, 0.f, 0.f, 0.f};
    acc2[1] = (f32x4){0.f, 0.f, 0.f, 0.f};
#pragma unroll
    for (int kc = 0; kc < 4; kc++) {
        size_t wo = ((size_t)(ct * 4 + kc) * 64 + lane) * 8;
        short8 bh = *(const short8*)&W2h[wo];
        short8 bl = *(const short8*)&W2l[wo];
#pragma unroll
        for (int rt = 0; rt < 2; rt++) {
            const short* ap = &t_hi[(rt * 16 + l15) * TS + kc * 32 + quad * 8];
            short8 ah = *(const short8*)ap;
            short8 al = *(const short8*)(ap + 32 * TS);
            acc2[rt] = __builtin_amdgcn_mfma_f32_16x16x32_bf16(ah, bh, acc2[rt], 0, 0, 0);
            acc2[rt] = __builtin_amdgcn_mfma_f32_16x16x32_bf16(al, bh, acc2[rt], 0, 0, 0);
            acc2[rt] = __builtin_amdgcn_mfma_f32_16x16x32_bf16(ah, bl, acc2[rt], 0, 0, 0);
        }
    }
#pragma unroll
    for (int rt = 0; rt < 2; rt++) {
#pragma unroll
        for (int rr = 0; rr < 4; rr++) {
            unsigned h, l;
            splitt(selu_f(acc2[rt][rr]), h, l);
            size_t o = (size_t)(e0 + rt * 16 + quad * 4 + rr) * 128 + col;
            zoh_s[o] = (short)h;
            zol_s[o] = (short)l;
        }
    }
}

// node MLP: g-gather via global_load_lds + selu-space segment max of z planes
__global__ __launch_bounds__(512) void k_node_mlp_mfma(
    const unsigned* __restrict__ gh_u, const unsigned* __restrict__ gl_u,
    short* __restrict__ goh_s, short* __restrict__ gol_s,
    const unsigned* __restrict__ zh_u, const unsigned* __restrict__ zl_u,
    const int* __restrict__ rowstart, const int2* __restrict__ csr_se,
    const short* __restrict__ W1h, const short* __restrict__ W1l,
    const short* __restrict__ W2h, const short* __restrict__ W2l) {
    __shared__ short smem[2 * 32 * MS_N];        // 33792 B
    short* m_hi = smem;
    short* m_lo = smem + 32 * MS_N;
    short* t_hi = smem;
    short* t_lo = smem + 32 * TS;
    const int tid = threadIdx.x;
    const int n0 = blockIdx.x * 32;
    const int lane = tid & 63, wave = tid >> 6;

    for (int t = wave; t < 32; t += 8) {
        int n = rfl(n0 + t);
        load_lds4(gh_u + (size_t)n * 64 + lane, &m_hi[t * MS_N]);
        load_lds4(gl_u + (size_t)n * 64 + lane, &m_lo[t * MS_N]);
    }
    for (int idx = tid; idx < 32 * 64; idx += 512) {
        int row = rfl(idx >> 6);              // wave-uniform each iteration
        int cp = idx & 63;
        int n = rfl(n0 + row);
        int p0 = rfl(rowstart[n]), p1 = rfl(rowstart[n + 1]);
        float b0 = -3.0e38f, b1 = -3.0e38f;
        unsigned bh0 = 0, bl0 = 0, bh1 = 0, bl1 = 0;  // default split(0)
        for (int p = p0; p < p1; p++) {
            int ey = rfl(csr_se[p].y);        // scalar edge index
            size_t o = (size_t)ey * 64 + cp;
            unsigned vh = zh_u[o], vl = zl_u[o];
            float f0 = __uint_as_float(vh << 16) + __uint_as_float(vl << 16);
            float f1 = __uint_as_float(vh & 0xffff0000u) + __uint_as_float(vl & 0xffff0000u);
            if (f0 > b0) { b0 = f0; bh0 = vh & 0xffffu; bl0 = vl & 0xffffu; }
            if (f1 > b1) { b1 = f1; bh1 = vh & 0xffff0000u; bl1 = vl & 0xffff0000u; }
        }
        int k = 128 + 2 * cp;
        *(unsigned*)&m_hi[row * MS_N + k] = bh0 | bh1;
        *(unsigned*)&m_lo[row * MS_N + k] = bl0 | bl1;
    }
    __syncthreads();

    const int ct = wave;
    const int l15 = lane & 15, quad = lane >> 4;
    const int col = ct * 16 + l15;

    f32x4 acc[2];
    acc[0] = (f32x4){0.f, 0.f, 0.f, 0.f};
    acc[1] = (f32x4){0.f, 0.f, 0.f, 0.f};
#pragma unroll 4
    for (int kc = 0; kc < 8; kc++) {
        size_t wo = ((size_t)(ct * 8 + kc) * 64 + lane) * 8;
        short8 bh = *(const short8*)&W1h[wo];
        short8 bl = *(const short8*)&W1l[wo];
#pragma unroll
        for (int rt = 0; rt < 2; rt++) {
            const short* ap = &m_hi[(rt * 16 + l15) * MS_N + kc * 32 + quad * 8];
            short8 ah = *(const short8*)ap;
            short8 al = *(const short8*)(ap + 32 * MS_N);
            acc[rt] = __builtin_amdgcn_mfma_f32_16x16x32_bf16(ah, bh, acc[rt], 0, 0, 0);
            acc[rt] = __builtin_amdgcn_mfma_f32_16x16x32_bf16(al, bh, acc[rt], 0, 0, 0);
            acc[rt] = __builtin_amdgcn_mfma_f32_16x16x32_bf16(ah, bl, acc[rt], 0, 0, 0);
        }
    }
    __syncthreads();
#pragma unroll
    for (int rt = 0; rt < 2; rt++) {
#pragma unroll
        for (int rr = 0; rr < 4; rr++) {
            unsigned h, l;
            splitt(selu_f(acc[rt][rr]), h, l);
            t_hi[(rt * 16 + quad * 4 + rr) * TS + col] = (short)h;
            t_lo[(rt * 16 + quad * 4 + rr) * TS + col] = (short)l;
        }
    }
    __syncthreads();

    f32x4 acc2[2];
    acc2[0] = (f32x4){0.f, 0.f, 0.f, 0.f};
    acc2[1] = (f32x4){0.f, 0.f, 0.f, 0.f};
#pragma unroll
    for (int kc = 0; kc < 4; kc++) {
        size_t wo = ((size_t)(ct * 4 + kc) * 64 + lane) * 8;
        short8 bh = *(const short8*)&W2h[wo];
        short8 bl = *(const short8*)&W2l[wo];
#pragma unroll
        for (int rt = 0; rt < 2; rt++) {
            const short* ap = &t_hi[(rt * 16 + l15) * TS + kc * 32 + quad * 8];
            short8 ah = *(const short8*)ap;
            short8 al = *(const short8*)(ap + 32 * TS);
            acc2[rt] = __builtin_amdgcn_mfma_f32_16x16x32_bf16(ah, bh, acc2[rt], 0, 0, 0);
            acc2[rt] = __builtin_amdgcn_mfma_f32_16x16x32_bf16(al, bh, acc2[rt], 0, 0, 0);
            acc2[rt] = __builtin_amdgcn_mfma_f32_16x16x32_bf16(ah, bl, acc2[rt], 0, 0, 0);
        }
    }
#pragma unroll
    for (int rt = 0; rt < 2; rt++) {
#pragma unroll
        for (int rr = 0; rr < 4; rr++) {
            unsigned h, l;
            splitt(selu_f(acc2[rt][rr]), h, l);
            size_t o = (size_t)(n0 + rt * 16 + quad * 4 + rr) * 128 + col;
            goh_s[o] = (short)h;
            gol_s[o] = (short)l;
        }
    }
}

// Wf chain on first-half edges: q_new = q_old + selu(selu(lam@Wf1)@Wf2)@Wf3;
// antisymmetrize; ALSO computes hl for both halves (hl[e+E2] = -hl[e]).
__global__ __launch_bounds__(512) void k_wf_mfma(
    const unsigned* __restrict__ gh_u, const unsigned* __restrict__ gl_u,
    const unsigned* __restrict__ zh_u, const unsigned* __restrict__ zl_u,
    const short* __restrict__ W1h, const short* __restrict__ W1l,
    const short* __restrict__ W2h, const short* __restrict__ W2l,
    const float* __restrict__ W3 /*[128]*/,
    const int* __restrict__ sndr, const int* __restrict__ rcvr,
    const float* __restrict__ r,
    float* __restrict__ qh, float* __restrict__ hl) {
    __shared__ short smem[2 * 32 * MS_E];
    __shared__ float red[32 * 8];
    short* m_hi = smem;
    short* m_lo = smem + 32 * MS_E;
    short* t_hi = smem;
    short* t_lo = smem + 32 * TS;
    const int tid = threadIdx.x;
    const int bi = blockIdx.x;
    const int x7 = bi & 7, jj = bi >> 3;
    const int fi0 = ((x7 >> 1) * 500 + (x7 & 1) * 250 + jj) * 32;
    const int b = fi0 / E2c;
    const int ebase = b * EPGc - b * E2c;     // e = ebase + fi
    const int lane = tid & 63, wave = tid >> 6;

    for (int t = wave; t < 96; t += 8) {
        int row = t & 31, region = t >> 5;
        int e = rfl(ebase + fi0 + row);
        size_t o;
        const unsigned *ph, *pl;
        if (region == 0)      { o = (size_t)rfl(sndr[e]) * 64; ph = gh_u; pl = gl_u; }
        else if (region == 1) { o = (size_t)rfl(rcvr[e]) * 64; ph = gh_u; pl = gl_u; }
        else                  { o = (size_t)e * 64;            ph = zh_u; pl = zl_u; }
        load_lds4(ph + o + lane, &m_hi[row * MS_E + region * 128]);
        load_lds4(pl + o + lane, &m_lo[row * MS_E + region * 128]);
    }
    __syncthreads();

    const int ct = wave;
    const int l15 = lane & 15, quad = lane >> 4;
    const int col = ct * 16 + l15;

    f32x4 acc[2];
    acc[0] = (f32x4){0.f, 0.f, 0.f, 0.f};
    acc[1] = (f32x4){0.f, 0.f, 0.f, 0.f};
#pragma unroll 4
    for (int kc = 0; kc < 12; kc++) {
        size_t wo = ((size_t)(ct * 12 + kc) * 64 + lane) * 8;
        short8 bh = *(const short8*)&W1h[wo];
        short8 bl = *(const short8*)&W1l[wo];
#pragma unroll
        for (int rt = 0; rt < 2; rt++) {
            const short* ap = &m_hi[(rt * 16 + l15) * MS_E + kc * 32 + quad * 8];
            short8 ah = *(const short8*)ap;
            short8 al = *(const short8*)(ap + 32 * MS_E);
            acc[rt] = __builtin_amdgcn_mfma_f32_16x16x32_bf16(ah, bh, acc[rt], 0, 0, 0);
            acc[rt] = __builtin_amdgcn_mfma_f32_16x16x32_bf16(al, bh, acc[rt], 0, 0, 0);
            acc[rt] = __builtin_amdgcn_mfma_f32_16x16x32_bf16(ah, bl, acc[rt], 0, 0, 0);
        }
    }
    __syncthreads();
#pragma unroll
    for (int rt = 0; rt < 2; rt++) {
#pragma unroll
        for (int rr = 0; rr < 4; rr++) {
            unsigned h, l;
            splitt(selu_f(acc[rt][rr]), h, l);
            t_hi[(rt * 16 + quad * 4 + rr) * TS + col] = (short)h;
            t_lo[(rt * 16 + quad * 4 + rr) * TS + col] = (short)l;
        }
    }
    __syncthreads();

    f32x4 acc2[2];
    acc2[0] = (f32x4){0.f, 0.f, 0.f, 0.f};
    acc2[1] = (f32x4){0.f, 0.f, 0.f, 0.f};
#pragma unroll
    for (int kc = 0; kc < 4; kc++) {
        size_t wo = ((size_t)(ct * 4 + kc) * 64 + lane) * 8;
        short8 bh = *(const short8*)&W2h[wo];
        short8 bl = *(const short8*)&W2l[wo];
#pragma unroll
        for (int rt = 0; rt < 2; rt++) {
            const short* ap = &t_hi[(rt * 16 + l15) * TS + kc * 32 + quad * 8];
            short8 ah = *(const short8*)ap;
            short8 al = *(const short8*)(ap + 32 * TS);
            acc2[rt] = __builtin_amdgcn_mfma_f32_16x16x32_bf16(ah, bh, acc2[rt], 0, 0, 0);
            acc2[rt] = __builtin_amdgcn_mfma_f32_16x16x32_bf16(al, bh, acc2[rt], 0, 0, 0);
            acc2[rt] = __builtin_amdgcn_mfma_f32_16x16x32_bf16(ah, bl, acc2[rt], 0, 0, 0);
        }
    }
    float w3 = W3[col];
    float p[8];
#pragma unroll
    for (int rt = 0; rt < 2; rt++)
#pragma unroll
        for (int rr = 0; rr < 4; rr++) p[rt * 4 + rr] = selu_f(acc2[rt][rr]) * w3;
#pragma unroll
    for (int off = 1; off < 16; off <<= 1) {
#pragma unroll
        for (int i = 0; i < 8; i++) p[i] += __shfl_xor(p[i], off, 64);
    }
    if (l15 == 0) {
#pragma unroll
        for (int rt = 0; rt < 2; rt++)
#pragma unroll
            for (int rr = 0; rr < 4; rr++)
                red[(rt * 16 + quad * 4 + rr) * 8 + ct] = p[rt * 4 + rr];
    }
    __syncthreads();
    if (tid < 32) {
        float f = 0.0f;
#pragma unroll
        for (int c = 0; c < 8; c++) f += red[tid * 8 + c];
        int e = ebase + fi0 + tid;
        float qn = qh[e] + f;
        qh[e] = qn;
        qh[e + E2c] = -qn;
        float hv = r[e] * signf(qn) * __powf(fabsf(qn), PEXPc);
        hl[e] = hv;
        hl[e + E2c] = -hv;
    }
}

// ---------------- host orchestration ----------------

extern "C" void kernel_launch(void* const* d_in, const int* in_sizes, int n_in,
                              void* d_out, int out_size, void* d_ws, size_t ws_size,
                              hipStream_t stream) {
    const float* x   = (const float*)d_in[0];
    const float* r   = (const float*)d_in[1];
    const float* Wni = (const float*)d_in[2];
    const float* Wei = (const float*)d_in[3];
    const float* Wf1 = (const float*)d_in[4];
    const float* Wf2 = (const float*)d_in[5];
    const float* Wf3 = (const float*)d_in[6];
    const float* We1 = (const float*)d_in[7];   // (3,384,128)
    const float* We2 = (const float*)d_in[8];   // (3,128,128)
    const float* Wn1 = (const float*)d_in[9];   // (3,256,128)
    const float* Wn2 = (const float*)d_in[10];  // (3,128,128)
    const int* sndr  = (const int*)d_in[11];
    const int* rcvr  = (const int*)d_in[12];
    float* out = (float*)d_out;

    char* wp = (char*)d_ws;
    auto carve = [&](size_t bytes) -> void* {
        void* ret = (void*)wp;
        wp += (bytes + 255) & ~(size_t)255;
        return ret;
    };
    unsigned* gh_u = (unsigned*)carve((size_t)NNc * 64 * 4);
    unsigned* gl_u = (unsigned*)carve((size_t)NNc * 64 * 4);
    unsigned* zAh  = (unsigned*)carve((size_t)NEc * 64 * 4);
    unsigned* zAl  = (unsigned*)carve((size_t)NEc * 64 * 4);
    unsigned* zBh  = (unsigned*)carve((size_t)NEc * 64 * 4);
    unsigned* zBl  = (unsigned*)carve((size_t)NEc * 64 * 4);
    float* qh     = (float*)carve((size_t)NEc * 4);
    float* qt     = (float*)carve((size_t)NEc * 4);
    float* hl     = (float*)carve((size_t)NEc * 4);
    float* hA     = (float*)carve((size_t)NNc * 4);
    float* hB     = (float*)carve((size_t)NNc * 4);
    int*   deg    = (int*)carve((size_t)NNc * 4);
    int*   cursor = (int*)carve((size_t)NNc * 4);
    int*   rowst  = (int*)carve((size_t)(NNc + 1) * 4);
    int*   part   = (int*)carve((size_t)NSB * 4);
    int2*  csr_se = (int2*)carve((size_t)NEc * 8);
    short* we1h   = (short*)carve((size_t)3 * 128 * 384 * 2);
    short* we1l   = (short*)carve((size_t)3 * 128 * 384 * 2);
    short* we2h   = (short*)carve((size_t)3 * 128 * 128 * 2);
    short* we2l   = (short*)carve((size_t)3 * 128 * 128 * 2);
    short* wn1h   = (short*)carve((size_t)3 * 128 * 256 * 2);
    short* wn1l   = (short*)carve((size_t)3 * 128 * 256 * 2);
    short* wn2h   = (short*)carve((size_t)3 * 128 * 128 * 2);
    short* wn2l   = (short*)carve((size_t)3 * 128 * 128 * 2);
    short* wf1h   = (short*)carve((size_t)128 * 384 * 2);
    short* wf1l   = (short*)carve((size_t)128 * 384 * 2);
    short* wf2h   = (short*)carve((size_t)128 * 128 * 2);
    short* wf2l   = (short*)carve((size_t)128 * 128 * 2);

    const int TB = 256;
    const int gN  = (NNc + TB - 1) / TB;
    const int gE  = (NEc + TB - 1) / TB;

    // fragment-linear weight planes (nkc = K/32)
    for (int i = 0; i < 3; i++) {
        k_wconv_frag<<<(8 * 12 * 64 + 255) / 256, TB, 0, stream>>>(We1 + (size_t)i * 384 * 128, we1h + (size_t)i * 128 * 384, we1l + (size_t)i * 128 * 384, 12);
        k_wconv_frag<<<(8 * 4 * 64 + 255) / 256, TB, 0, stream>>>(We2 + (size_t)i * 128 * 128, we2h + (size_t)i * 128 * 128, we2l + (size_t)i * 128 * 128, 4);
        k_wconv_frag<<<(8 * 8 * 64 + 255) / 256, TB, 0, stream>>>(Wn1 + (size_t)i * 256 * 128, wn1h + (size_t)i * 128 * 256, wn1l + (size_t)i * 128 * 256, 8);
        k_wconv_frag<<<(8 * 4 * 64 + 255) / 256, TB, 0, stream>>>(Wn2 + (size_t)i * 128 * 128, wn2h + (size_t)i * 128 * 128, wn2l + (size_t)i * 128 * 128, 4);
    }
    k_wconv_frag<<<(8 * 12 * 64 + 255) / 256, TB, 0, stream>>>(Wf1, wf1h, wf1l, 12);
    k_wconv_frag<<<(8 * 4 * 64 + 255) / 256, TB, 0, stream>>>(Wf2, wf2h, wf2l, 4);

    // CSR build (multi-block scan)
    k_zero_i<<<gN, TB, 0, stream>>>(deg, NNc);
    k_count<<<gE, TB, 0, stream>>>(rcvr, deg);
    k_scan1<<<NSB, TB, 0, stream>>>(deg, part);
    k_scan2<<<1, TB, 0, stream>>>(part);
    k_scan3<<<NSB, TB, 0, stream>>>(deg, part, rowst, cursor);
    k_scatter<<<gE, TB, 0, stream>>>(sndr, rcvr, cursor, csr_se);

    // initial flows
    k_qinit<<<gE, TB, 0, stream>>>(x, r, sndr, rcvr, qh, qt);

    const int gH = (NNc + 63) / 64;
    for (int kit = 0; kit < 4; kit++) {
        k_node_in_f<<<(NNc + 3) / 4, TB, 0, stream>>>(qh, rowst, csr_se, x, Wni, gh_u, gl_u);
        unsigned *zin_h = zAh, *zin_l = zAl, *zout_h = zAh, *zout_l = zAl;
        for (int i = 0; i < 3; i++) {
            zin_h = zout_h; zin_l = zout_l;
            zout_h = (i & 1) ? zAh : zBh;
            zout_l = (i & 1) ? zAl : zBl;
            k_edge_mlp_mfma<<<NEc / 32, 512, 0, stream>>>(
                gh_u, gl_u, zin_h, zin_l, (short*)zout_h, (short*)zout_l,
                we1h + (size_t)i * 128 * 384, we1l + (size_t)i * 128 * 384,
                we2h + (size_t)i * 128 * 128, we2l + (size_t)i * 128 * 128,
                sndr, rcvr, qt, qh, Wei, (i == 0) ? 1 : 0);
            k_node_mlp_mfma<<<NNc / 32, 512, 0, stream>>>(
                gh_u, gl_u, (short*)gh_u, (short*)gl_u, zout_h, zout_l, rowst, csr_se,
                wn1h + (size_t)i * 128 * 256, wn1l + (size_t)i * 128 * 256,
                wn2h + (size_t)i * 128 * 128, wn2l + (size_t)i * 128 * 128);
        }
        k_wf_mfma<<<(4 * E2c) / 32, 512, 0, stream>>>(
            gh_u, gl_u, zout_h, zout_l, wf1h, wf1l, wf2h, wf2l, Wf3, sndr, rcvr,
            r, qh, hl);
        // head propagation: 6 iterations; first reads h_star straight from x (stride 2)
        const float* hin = x; int hstride = 2;
        float* cur = hA;
        for (int jh = 0; jh < 6; jh++) {
            float* dst = (jh == 5) ? ((kit == 3) ? out : hB) : cur;
            k_head_iter<<<gH, 64, 0, stream>>>(x, hin, hstride, hl, rowst, csr_se, dst);
            hin = dst; hstride = 1;
            cur = (dst == hA) ? hB : hA;
        }
        if (kit < 3) k_flows_q<<<gE, TB, 0, stream>>>(hB, r, sndr, rcvr, qt);
    }
}

// Round 16
// 1886.710 us; speedup vs baseline: 1.6554x; 1.0054x over previous
//
#include <hip/hip_runtime.h>
#include <hip/hip_bf16.h>
#include <math.h>

// Problem constants
#define NPGc  10000
#define EPGc  32000
#define MLc   128
#define NNc   40000      // N
#define NEc   128000     // E
#define E2c   16000      // EPG/2
#define ZETAc 1e-6f
#define INVPc 0.53995680345572354f   // 1/1.852
#define PEXPc 1.852f
#define NSB   ((NNc + 255) / 256)    // 157 scan blocks

typedef __attribute__((ext_vector_type(8))) short short8;   // 8 bf16 (4 VGPRs)
typedef __attribute__((ext_vector_type(4))) float f32x4;    // MFMA acc

// fast selu: __expf -> v_exp_f32
__device__ __forceinline__ float selu_f(float x) {
    float e = __expf(x) - 1.0f;
    return 1.0507009873554805f * (x > 0.0f ? x : 1.6732632423543772f * e);
}
// cheap split fp32 -> (hi, lo): hi = truncated top-16 bits (exact rem), lo = RNE(rem).
__device__ __forceinline__ void splitt(float v, unsigned& hi, unsigned& lo) {
    unsigned u = __float_as_uint(v);
    hi = u >> 16;
    float rem = v - __uint_as_float(u & 0xffff0000u);
    __hip_bfloat16 l = __float2bfloat16(rem);
    lo = (unsigned short)*reinterpret_cast<short*>(&l);
}
__device__ __forceinline__ float signf(float x) {
    return (x > 0.0f) ? 1.0f : (x < 0.0f ? -1.0f : 0.0f);
}
__device__ __forceinline__ int rfl(int v) { return __builtin_amdgcn_readfirstlane(v); }

// async global->LDS: 64 lanes x 4B, wave-uniform LDS base + lane*4
__device__ __forceinline__ void load_lds4(const unsigned* src, short* dst) {
    __builtin_amdgcn_global_load_lds(
        (const __attribute__((address_space(1))) unsigned*)src,
        (__attribute__((address_space(3))) unsigned*)dst, 4, 0, 0);
}

// ---------------- weight convert+split into MFMA B-FRAGMENT-LINEAR layout ------------
// B-frag for mfma_16x16x32: n = ct*16 + (lane&15), k = kc*32 + (lane>>4)*8 + j.
__global__ void k_wconv_frag(const float* __restrict__ src, short* __restrict__ dh,
                             short* __restrict__ dl, int nkc /* = K/32 */) {
    int gid = blockIdx.x * 256 + threadIdx.x;   // one thread per (frag, lane)
    int total = 8 * nkc * 64;                   // ct(8) x kc(nkc) x lane(64)
    if (gid >= total) return;
    int lane = gid & 63;
    int frag = gid >> 6;
    int kc = frag % nkc;
    int ct = frag / nkc;
    int col = ct * 16 + (lane & 15);
    int kbase = kc * 32 + (lane >> 4) * 8;
    size_t o = (size_t)gid * 8;
#pragma unroll
    for (int j = 0; j < 8; j++) {
        unsigned h, l;
        splitt(src[(size_t)(kbase + j) * 128 + col], h, l);
        dh[o + j] = (short)h;
        dl[o + j] = (short)l;
    }
}

// ---------------- CSR build (by rcvr) ----------------
__global__ void k_zero_i(int* p, int n) {
    int i = blockIdx.x * 256 + threadIdx.x;
    if (i < n) p[i] = 0;
}
__global__ void k_count(const int* __restrict__ rcvr, int* __restrict__ deg) {
    int e = blockIdx.x * 256 + threadIdx.x;
    if (e < NEc) atomicAdd(&deg[rcvr[e]], 1);
}
// 3-phase multi-block exclusive scan
__global__ void k_scan1(const int* __restrict__ deg, int* __restrict__ partial) {
    __shared__ int buf[256];
    int t = threadIdx.x;
    int i = blockIdx.x * 256 + t;
    buf[t] = (i < NNc) ? deg[i] : 0;
    __syncthreads();
    for (int off = 128; off > 0; off >>= 1) {
        if (t < off) buf[t] += buf[t + off];
        __syncthreads();
    }
    if (t == 0) partial[blockIdx.x] = buf[0];
}
__global__ void k_scan2(int* __restrict__ partial) {
    __shared__ int buf[256];
    int t = threadIdx.x;
    int v = (t < NSB) ? partial[t] : 0;
    buf[t] = v;
    __syncthreads();
    for (int off = 1; off < 256; off <<= 1) {
        int u = (t >= off) ? buf[t - off] : 0;
        __syncthreads();
        buf[t] += u;
        __syncthreads();
    }
    if (t < NSB) partial[t] = buf[t] - v;   // exclusive
}
__global__ void k_scan3(const int* __restrict__ deg, const int* __restrict__ partial,
                        int* __restrict__ rowstart, int* __restrict__ cursor) {
    __shared__ int buf[256];
    int t = threadIdx.x;
    int i = blockIdx.x * 256 + t;
    int v = (i < NNc) ? deg[i] : 0;
    buf[t] = v;
    __syncthreads();
    for (int off = 1; off < 256; off <<= 1) {
        int u = (t >= off) ? buf[t - off] : 0;
        __syncthreads();
        buf[t] += u;
        __syncthreads();
    }
    int excl = partial[blockIdx.x] + buf[t] - v;
    if (i < NNc) { rowstart[i] = excl; cursor[i] = excl; }
    if (i == NNc - 1) rowstart[NNc] = excl + v;
}
__global__ void k_scatter(const int* __restrict__ sndr, const int* __restrict__ rcvr,
                          int* __restrict__ cursor, int2* __restrict__ csr_se) {
    int e = blockIdx.x * 256 + threadIdx.x;
    if (e >= NEc) return;
    int rv = rcvr[e];
    int p = atomicAdd(&cursor[rv], 1);
    csr_se[p] = make_int2(sndr[e], e);
}

// ---------------- flows / elementwise ----------------
__global__ void k_qinit(const float* __restrict__ x, const float* __restrict__ r,
                        const int* __restrict__ sndr, const int* __restrict__ rcvr,
                        float* __restrict__ qh, float* __restrict__ qt) {
    int e = blockIdx.x * 256 + threadIdx.x;
    if (e >= NEc) return;
    float hv = x[2 * sndr[e]] - x[2 * rcvr[e]];
    float q = signf(hv) * __powf((fabsf(hv) + ZETAc) / (r[e] + ZETAc), INVPc);
    qh[e] = q; qt[e] = q;
}
__global__ void k_flows_q(const float* __restrict__ h, const float* __restrict__ r,
                          const int* __restrict__ sndr, const int* __restrict__ rcvr,
                          float* __restrict__ qt) {
    int e = blockIdx.x * 256 + threadIdx.x;
    if (e >= NEc) return;
    float hv = h[sndr[e]] - h[rcvr[e]];
    qt[e] = signf(hv) * __powf((fabsf(hv) + ZETAc) / (r[e] + ZETAc), INVPc);
}

// node-in, fused segsum: one WAVE per node. Produces split-selu g planes.
__global__ __launch_bounds__(256) void k_node_in_f(
    const float* __restrict__ qh, const int* __restrict__ rowstart,
    const int2* __restrict__ csr_se, const float* __restrict__ x,
    const float* __restrict__ W /*2x128*/,
    unsigned* __restrict__ gh_u, unsigned* __restrict__ gl_u) {
    const int tid = threadIdx.x;
    const int lane = tid & 63;
    const int n = rfl(blockIdx.x * 4 + (tid >> 6));
    if (n >= NNc) return;
    int p0 = rfl(rowstart[n]), p1 = rfl(rowstart[n + 1]);
    float s = 0.0f;
    for (int p = p0 + lane; p < p1; p += 64) s += qh[csr_se[p].y];
#pragma unroll
    for (int off = 1; off < 64; off <<= 1) s += __shfl_xor(s, off, 64);
    float s0 = selu_f(s);
    float s1 = selu_f(x[2 * n + 1]);
    int c = lane * 2;
    float g0 = s0 * W[c]     + s1 * W[MLc + c];
    float g1 = s0 * W[c + 1] + s1 * W[MLc + c + 1];
    unsigned h0, l0, h1, l1;
    splitt(selu_f(g0), h0, l0);
    splitt(selu_f(g1), h1, l1);
    gh_u[(size_t)n * 64 + lane] = h0 | (h1 << 16);
    gl_u[(size_t)n * 64 + lane] = l0 | (l1 << 16);
}

// one head-propagation iteration, CSR gather; hin has stride (2 for x, 1 for h buf)
__global__ __launch_bounds__(64) void k_head_iter(
    const float* __restrict__ x, const float* __restrict__ hin, int hstride,
    const float* __restrict__ hl, const int* __restrict__ rowstart,
    const int2* __restrict__ csr_se, float* __restrict__ hout) {
    int n = blockIdx.x * 64 + threadIdx.x;
    if (n >= NNc) return;
    float hv = hin[(size_t)n * hstride];
    float m = -3.0e38f;
    int p0 = rowstart[n], p1 = rowstart[n + 1];
    for (int p = p0; p < p1; p++) {
        int2 se = csr_se[p];
        m = fmaxf(m, hin[(size_t)se.x * hstride] - hl[se.y]);
    }
    float a = (m > -1e30f) ? m : hv;
    float hstar = x[2 * n];
    hout[n] = (hstar != 0.0f) ? hstar : fmaxf(hv, a);
}

// ---------------- split-bf16 MFMA MLP kernels ----------------
// 32-row tile, 512 threads = 8 waves; wave = 16-col tile x both 16-row tiles.
// Staging addresses scalarized via readfirstlane (s_load + SALU, saddr-form DMA).
// A-frag: row=lane&15, k=quad*8+j. C/D: col=lane&15, row=quad*4+reg.

#define MS_E 392   // 384+8 shorts
#define MS_N 264   // 256+8
#define TS   136   // 128+8

__global__ __launch_bounds__(512) void k_edge_mlp_mfma(
    const unsigned* __restrict__ gh_u, const unsigned* __restrict__ gl_u,
    const unsigned* __restrict__ zh_u, const unsigned* __restrict__ zl_u,
    short* __restrict__ zoh_s, short* __restrict__ zol_s,
    const short* __restrict__ W1h, const short* __restrict__ W1l,
    const short* __restrict__ W2h, const short* __restrict__ W2l,
    const int* __restrict__ sndr, const int* __restrict__ rcvr,
    const float* __restrict__ qt, const float* __restrict__ qh,
    const float* __restrict__ Wei, int zmode) {
    __shared__ short smem[2 * 32 * MS_E];        // 50176 B
    short* m_hi = smem;
    short* m_lo = smem + 32 * MS_E;
    short* t_hi = smem;                          // alias front (post-barrier)
    short* t_lo = smem + 32 * TS;
    const int tid = threadIdx.x;
    const int bi = blockIdx.x;
    const int x7 = bi & 7, jj = bi >> 3;
    const int e0 = ((x7 >> 1) * 1000 + (x7 & 1) * 500 + jj) * 32;   // XCD swizzle
    const int lane = tid & 63, wave = tid >> 6;

    if (zmode == 0) {
        for (int t = wave; t < 96; t += 8) {
            int row = t & 31, region = t >> 5;
            int e = rfl(e0 + row);
            size_t o;
            const unsigned *ph, *pl;
            if (region == 0)      { o = (size_t)rfl(sndr[e]) * 64; ph = gh_u; pl = gl_u; }
            else if (region == 1) { o = (size_t)rfl(rcvr[e]) * 64; ph = gh_u; pl = gl_u; }
            else                  { o = (size_t)e * 64;            ph = zh_u; pl = zl_u; }
            load_lds4(ph + o + lane, &m_hi[row * MS_E + region * 128]);
            load_lds4(pl + o + lane, &m_lo[row * MS_E + region * 128]);
        }
    } else {
        for (int t = wave; t < 64; t += 8) {
            int row = t & 31, region = t >> 5;
            int e = rfl(e0 + row);
            size_t o = (size_t)rfl(region == 0 ? sndr[e] : rcvr[e]) * 64;
            load_lds4(gh_u + o + lane, &m_hi[row * MS_E + region * 128]);
            load_lds4(gl_u + o + lane, &m_lo[row * MS_E + region * 128]);
        }
        // one row per 16-thread slice: selu(qt/qh) computed ONCE per thread
        {
            int row = tid >> 4;            // 32 rows x 16 threads
            int sub = tid & 15;            // 8 col-pairs each
            int e = e0 + row;
            float sqt = selu_f(qt[e]), sqh = selu_f(qh[e]);
#pragma unroll
            for (int jcp = 0; jcp < 4; jcp++) {
                int cp = sub * 4 + jcp;
                int c = 2 * cp;
                float z0 = sqt * Wei[c]     + sqh * Wei[MLc + c];
                float z1 = sqt * Wei[c + 1] + sqh * Wei[MLc + c + 1];
                unsigned h0, l0, h1, l1;
                splitt(selu_f(z0), h0, l0);
                splitt(selu_f(z1), h1, l1);
                int k = 256 + 2 * cp;
                *(unsigned*)&m_hi[row * MS_E + k] = h0 | (h1 << 16);
                *(unsigned*)&m_lo[row * MS_E + k] = l0 | (l1 << 16);
            }
        }
    }
    __syncthreads();

    const int ct = wave;
    const int l15 = lane & 15, quad = lane >> 4;
    const int col = ct * 16 + l15;

    f32x4 acc[2];
    acc[0] = (f32x4){0.f, 0.f, 0.f, 0.f};
    acc[1] = (f32x4){0.f, 0.f, 0.f, 0.f};
#pragma unroll 4
    for (int kc = 0; kc < 12; kc++) {
        size_t wo = ((size_t)(ct * 12 + kc) * 64 + lane) * 8;   // fragment-linear
        short8 bh = *(const short8*)&W1h[wo];
        short8 bl = *(const short8*)&W1l[wo];
#pragma unroll
        for (int rt = 0; rt < 2; rt++) {
            const short* ap = &m_hi[(rt * 16 + l15) * MS_E + kc * 32 + quad * 8];
            short8 ah = *(const short8*)ap;
            short8 al = *(const short8*)(ap + 32 * MS_E);
            acc[rt] = __builtin_amdgcn_mfma_f32_16x16x32_bf16(ah, bh, acc[rt], 0, 0, 0);
            acc[rt] = __builtin_amdgcn_mfma_f32_16x16x32_bf16(al, bh, acc[rt], 0, 0, 0);
            acc[rt] = __builtin_amdgcn_mfma_f32_16x16x32_bf16(ah, bl, acc[rt], 0, 0, 0);
        }
    }
    __syncthreads();
#pragma unroll
    for (int rt = 0; rt < 2; rt++) {
#pragma unroll
        for (int rr = 0; rr < 4; rr++) {
            unsigned h, l;
            splitt(selu_f(acc[rt][rr]), h, l);
            t_hi[(rt * 16 + quad * 4 + rr) * TS + col] = (short)h;
            t_lo[(rt * 16 + quad * 4 + rr) * TS + col] = (short)l;
        }
    }
    __syncthreads();

    f32x4 acc2[2];
    acc2[0] = (f32x4){0.f, 0.f, 0.f, 0.f};
    acc2[1] = (f32x4){0.f, 0.f, 0.f, 0.f};
#pragma unroll
    for (int kc = 0; kc < 4; kc++) {
        size_t wo = ((size_t)(ct * 4 + kc) * 64 + lane) * 8;
        short8 bh = *(const short8*)&W2h[wo];
        short8 bl = *(const short8*)&W2l[wo];
#pragma unroll
        for (int rt = 0; rt < 2; rt++) {
            const short* ap = &t_hi[(rt * 16 + l15) * TS + kc * 32 + quad * 8];
            short8 ah = *(const short8*)ap;
            short8 al = *(const short8*)(ap + 32 * TS);
            acc2[rt] = __builtin_amdgcn_mfma_f32_16x16x32_bf16(ah, bh, acc2[rt], 0, 0, 0);
            acc2[rt] = __builtin_amdgcn_mfma_f32_16x16x32_bf16(al, bh, acc2[rt], 0, 0, 0);
            acc2[rt] = __builtin_amdgcn_mfma_f32_16x16x32_bf16(ah, bl, acc2[rt], 0, 0, 0);
        }
    }
#pragma unroll
    for (int rt = 0; rt < 2; rt++) {
#pragma unroll
        for (int rr = 0; rr < 4; rr++) {
            unsigned h, l;
            splitt(selu_f(acc2[rt][rr]), h, l);
            size_t o = (size_t)(e0 + rt * 16 + quad * 4 + rr) * 128 + col;
            zoh_s[o] = (short)h;
            zol_s[o] = (short)l;
        }
    }
}

// node MLP: g-gather via global_load_lds + selu-space segment max of z planes
__global__ __launch_bounds__(512) void k_node_mlp_mfma(
    const unsigned* __restrict__ gh_u, const unsigned* __restrict__ gl_u,
    short* __restrict__ goh_s, short* __restrict__ gol_s,
    const unsigned* __restrict__ zh_u, const unsigned* __restrict__ zl_u,
    const int* __restrict__ rowstart, const int2* __restrict__ csr_se,
    const short* __restrict__ W1h, const short* __restrict__ W1l,
    const short* __restrict__ W2h, const short* __restrict__ W2l) {
    __shared__ short smem[2 * 32 * MS_N];        // 33792 B
    short* m_hi = smem;
    short* m_lo = smem + 32 * MS_N;
    short* t_hi = smem;
    short* t_lo = smem + 32 * TS;
    const int tid = threadIdx.x;
    const int n0 = blockIdx.x * 32;
    const int lane = tid & 63, wave = tid >> 6;

    for (int t = wave; t < 32; t += 8) {
        int n = rfl(n0 + t);
        load_lds4(gh_u + (size_t)n * 64 + lane, &m_hi[t * MS_N]);
        load_lds4(gl_u + (size_t)n * 64 + lane, &m_lo[t * MS_N]);
    }
    for (int idx = tid; idx < 32 * 64; idx += 512) {
        int row = rfl(idx >> 6);              // wave-uniform each iteration
        int cp = idx & 63;
        int n = rfl(n0 + row);
        int p0 = rfl(rowstart[n]), p1 = rfl(rowstart[n + 1]);
        float b0 = -3.0e38f, b1 = -3.0e38f;
        unsigned bh0 = 0, bl0 = 0, bh1 = 0, bl1 = 0;  // default split(0)
        for (int p = p0; p < p1; p++) {
            int ey = rfl(csr_se[p].y);        // scalar edge index
            size_t o = (size_t)ey * 64 + cp;
            unsigned vh = zh_u[o], vl = zl_u[o];
            float f0 = __uint_as_float(vh << 16) + __uint_as_float(vl << 16);
            float f1 = __uint_as_float(vh & 0xffff0000u) + __uint_as_float(vl & 0xffff0000u);
            if (f0 > b0) { b0 = f0; bh0 = vh & 0xffffu; bl0 = vl & 0xffffu; }
            if (f1 > b1) { b1 = f1; bh1 = vh & 0xffff0000u; bl1 = vl & 0xffff0000u; }
        }
        int k = 128 + 2 * cp;
        *(unsigned*)&m_hi[row * MS_N + k] = bh0 | bh1;
        *(unsigned*)&m_lo[row * MS_N + k] = bl0 | bl1;
    }
    __syncthreads();

    const int ct = wave;
    const int l15 = lane & 15, quad = lane >> 4;
    const int col = ct * 16 + l15;

    f32x4 acc[2];
    acc[0] = (f32x4){0.f, 0.f, 0.f, 0.f};
    acc[1] = (f32x4){0.f, 0.f, 0.f, 0.f};
#pragma unroll 4
    for (int kc = 0; kc < 8; kc++) {
        size_t wo = ((size_t)(ct * 8 + kc) * 64 + lane) * 8;
        short8 bh = *(const short8*)&W1h[wo];
        short8 bl = *(const short8*)&W1l[wo];
#pragma unroll
        for (int rt = 0; rt < 2; rt++) {
            const short* ap = &m_hi[(rt * 16 + l15) * MS_N + kc * 32 + quad * 8];
            short8 ah = *(const short8*)ap;
            short8 al = *(const short8*)(ap + 32 * MS_N);
            acc[rt] = __builtin_amdgcn_mfma_f32_16x16x32_bf16(ah, bh, acc[rt], 0, 0, 0);
            acc[rt] = __builtin_amdgcn_mfma_f32_16x16x32_bf16(al, bh, acc[rt], 0, 0, 0);
            acc[rt] = __builtin_amdgcn_mfma_f32_16x16x32_bf16(ah, bl, acc[rt], 0, 0, 0);
        }
    }
    __syncthreads();
#pragma unroll
    for (int rt = 0; rt < 2; rt++) {
#pragma unroll
        for (int rr = 0; rr < 4; rr++) {
            unsigned h, l;
            splitt(selu_f(acc[rt][rr]), h, l);
            t_hi[(rt * 16 + quad * 4 + rr) * TS + col] = (short)h;
            t_lo[(rt * 16 + quad * 4 + rr) * TS + col] = (short)l;
        }
    }
    __syncthreads();

    f32x4 acc2[2];
    acc2[0] = (f32x4){0.f, 0.f, 0.f, 0.f};
    acc2[1] = (f32x4){0.f, 0.f, 0.f, 0.f};
#pragma unroll
    for (int kc = 0; kc < 4; kc++) {
        size_t wo = ((size_t)(ct * 4 + kc) * 64 + lane) * 8;
        short8 bh = *(const short8*)&W2h[wo];
        short8 bl = *(const short8*)&W2l[wo];
#pragma unroll
        for (int rt = 0; rt < 2; rt++) {
            const short* ap = &t_hi[(rt * 16 + l15) * TS + kc * 32 + quad * 8];
            short8 ah = *(const short8*)ap;
            short8 al = *(const short8*)(ap + 32 * TS);
            acc2[rt] = __builtin_amdgcn_mfma_f32_16x16x32_bf16(ah, bh, acc2[rt], 0, 0, 0);
            acc2[rt] = __builtin_amdgcn_mfma_f32_16x16x32_bf16(al, bh, acc2[rt], 0, 0, 0);
            acc2[rt] = __builtin_amdgcn_mfma_f32_16x16x32_bf16(ah, bl, acc2[rt], 0, 0, 0);
        }
    }
#pragma unroll
    for (int rt = 0; rt < 2; rt++) {
#pragma unroll
        for (int rr = 0; rr < 4; rr++) {
            unsigned h, l;
            splitt(selu_f(acc2[rt][rr]), h, l);
            size_t o = (size_t)(n0 + rt * 16 + quad * 4 + rr) * 128 + col;
            goh_s[o] = (short)h;
            gol_s[o] = (short)l;
        }
    }
}

// Wf chain on first-half edges: q_new = q_old + selu(selu(lam@Wf1)@Wf2)@Wf3;
// antisymmetrize; ALSO computes hl for both halves (hl[e+E2] = -hl[e]).
__global__ __launch_bounds__(512) void k_wf_mfma(
    const unsigned* __restrict__ gh_u, const unsigned* __restrict__ gl_u,
    const unsigned* __restrict__ zh_u, const unsigned* __restrict__ zl_u,
    const short* __restrict__ W1h, const short* __restrict__ W1l,
    const short* __restrict__ W2h, const short* __restrict__ W2l,
    const float* __restrict__ W3 /*[128]*/,
    const int* __restrict__ sndr, const int* __restrict__ rcvr,
    const float* __restrict__ r,
    float* __restrict__ qh, float* __restrict__ hl) {
    __shared__ short smem[2 * 32 * MS_E];
    __shared__ float red[32 * 8];
    short* m_hi = smem;
    short* m_lo = smem + 32 * MS_E;
    short* t_hi = smem;
    short* t_lo = smem + 32 * TS;
    const int tid = threadIdx.x;
    const int bi = blockIdx.x;
    const int x7 = bi & 7, jj = bi >> 3;
    const int fi0 = ((x7 >> 1) * 500 + (x7 & 1) * 250 + jj) * 32;
    const int b = fi0 / E2c;
    const int ebase = b * EPGc - b * E2c;     // e = ebase + fi
    const int lane = tid & 63, wave = tid >> 6;

    for (int t = wave; t < 96; t += 8) {
        int row = t & 31, region = t >> 5;
        int e = rfl(ebase + fi0 + row);
        size_t o;
        const unsigned *ph, *pl;
        if (region == 0)      { o = (size_t)rfl(sndr[e]) * 64; ph = gh_u; pl = gl_u; }
        else if (region == 1) { o = (size_t)rfl(rcvr[e]) * 64; ph = gh_u; pl = gl_u; }
        else                  { o = (size_t)e * 64;            ph = zh_u; pl = zl_u; }
        load_lds4(ph + o + lane, &m_hi[row * MS_E + region * 128]);
        load_lds4(pl + o + lane, &m_lo[row * MS_E + region * 128]);
    }
    __syncthreads();

    const int ct = wave;
    const int l15 = lane & 15, quad = lane >> 4;
    const int col = ct * 16 + l15;

    f32x4 acc[2];
    acc[0] = (f32x4){0.f, 0.f, 0.f, 0.f};
    acc[1] = (f32x4){0.f, 0.f, 0.f, 0.f};
#pragma unroll 4
    for (int kc = 0; kc < 12; kc++) {
        size_t wo = ((size_t)(ct * 12 + kc) * 64 + lane) * 8;
        short8 bh = *(const short8*)&W1h[wo];
        short8 bl = *(const short8*)&W1l[wo];
#pragma unroll
        for (int rt = 0; rt < 2; rt++) {
            const short* ap = &m_hi[(rt * 16 + l15) * MS_E + kc * 32 + quad * 8];
            short8 ah = *(const short8*)ap;
            short8 al = *(const short8*)(ap + 32 * MS_E);
            acc[rt] = __builtin_amdgcn_mfma_f32_16x16x32_bf16(ah, bh, acc[rt], 0, 0, 0);
            acc[rt] = __builtin_amdgcn_mfma_f32_16x16x32_bf16(al, bh, acc[rt], 0, 0, 0);
            acc[rt] = __builtin_amdgcn_mfma_f32_16x16x32_bf16(ah, bl, acc[rt], 0, 0, 0);
        }
    }
    __syncthreads();
#pragma unroll
    for (int rt = 0; rt < 2; rt++) {
#pragma unroll
        for (int rr = 0; rr < 4; rr++) {
            unsigned h, l;
            splitt(selu_f(acc[rt][rr]), h, l);
            t_hi[(rt * 16 + quad * 4 + rr) * TS + col] = (short)h;
            t_lo[(rt * 16 + quad * 4 + rr) * TS + col] = (short)l;
        }
    }
    __syncthreads();

    f32x4 acc2[2];
    acc2[0] = (f32x4){0.f, 0.f, 0.f, 0.f};
    acc2[1] = (f32x4){0.f, 0.f, 0.f, 0.f};
#pragma unroll
    for (int kc = 0; kc < 4; kc++) {
        size_t wo = ((size_t)(ct * 4 + kc) * 64 + lane) * 8;
        short8 bh = *(const short8*)&W2h[wo];
        short8 bl = *(const short8*)&W2l[wo];
#pragma unroll
        for (int rt = 0; rt < 2; rt++) {
            const short* ap = &t_hi[(rt * 16 + l15) * TS + kc * 32 + quad * 8];
            short8 ah = *(const short8*)ap;
            short8 al = *(const short8*)(ap + 32 * TS);
            acc2[rt] = __builtin_amdgcn_mfma_f32_16x16x32_bf16(ah, bh, acc2[rt], 0, 0, 0);
            acc2[rt] = __builtin_amdgcn_mfma_f32_16x16x32_bf16(al, bh, acc2[rt], 0, 0, 0);
            acc2[rt] = __builtin_amdgcn_mfma_f32_16x16x32_bf16(ah, bl, acc2[rt], 0, 0, 0);
        }
    }
    float w3 = W3[col];
    float p[8];
#pragma unroll
    for (int rt = 0; rt < 2; rt++)
#pragma unroll
        for (int rr = 0; rr < 4; rr++) p[rt * 4 + rr] = selu_f(acc2[rt][rr]) * w3;
#pragma unroll
    for (int off = 1; off < 16; off <<= 1) {
#pragma unroll
        for (int i = 0; i < 8; i++) p[i] += __shfl_xor(p[i], off, 64);
    }
    if (l15 == 0) {
#pragma unroll
        for (int rt = 0; rt < 2; rt++)
#pragma unroll
            for (int rr = 0; rr < 4; rr++)
                red[(rt * 16 + quad * 4 + rr) * 8 + ct] = p[rt * 4 + rr];
    }
    __syncthreads();
    if (tid < 32) {
        float f = 0.0f;
#pragma unroll
        for (int c = 0; c < 8; c++) f += red[tid * 8 + c];
        int e = ebase + fi0 + tid;
        float qn = qh[e] + f;
        qh[e] = qn;
        qh[e + E2c] = -qn;
        float hv = r[e] * signf(qn) * __powf(fabsf(qn), PEXPc);
        hl[e] = hv;
        hl[e + E2c] = -hv;
    }
}

// ---------------- host orchestration ----------------

extern "C" void kernel_launch(void* const* d_in, const int* in_sizes, int n_in,
                              void* d_out, int out_size, void* d_ws, size_t ws_size,
                              hipStream_t stream) {
    const float* x   = (const float*)d_in[0];
    const float* r   = (const float*)d_in[1];
    const float* Wni = (const float*)d_in[2];
    const float* Wei = (const float*)d_in[3];
    const float* Wf1 = (const float*)d_in[4];
    const float* Wf2 = (const float*)d_in[5];
    const float* Wf3 = (const float*)d_in[6];
    const float* We1 = (const float*)d_in[7];   // (3,384,128)
    const float* We2 = (const float*)d_in[8];   // (3,128,128)
    const float* Wn1 = (const float*)d_in[9];   // (3,256,128)
    const float* Wn2 = (const float*)d_in[10];  // (3,128,128)
    const int* sndr  = (const int*)d_in[11];
    const int* rcvr  = (const int*)d_in[12];
    float* out = (float*)d_out;

    char* wp = (char*)d_ws;
    auto carve = [&](size_t bytes) -> void* {
        void* ret = (void*)wp;
        wp += (bytes + 255) & ~(size_t)255;
        return ret;
    };
    unsigned* gh_u = (unsigned*)carve((size_t)NNc * 64 * 4);
    unsigned* gl_u = (unsigned*)carve((size_t)NNc * 64 * 4);
    unsigned* zAh  = (unsigned*)carve((size_t)NEc * 64 * 4);
    unsigned* zAl  = (unsigned*)carve((size_t)NEc * 64 * 4);
    unsigned* zBh  = (unsigned*)carve((size_t)NEc * 64 * 4);
    unsigned* zBl  = (unsigned*)carve((size_t)NEc * 64 * 4);
    float* qh     = (float*)carve((size_t)NEc * 4);
    float* qt     = (float*)carve((size_t)NEc * 4);
    float* hl     = (float*)carve((size_t)NEc * 4);
    float* hA     = (float*)carve((size_t)NNc * 4);
    float* hB     = (float*)carve((size_t)NNc * 4);
    int*   deg    = (int*)carve((size_t)NNc * 4);
    int*   cursor = (int*)carve((size_t)NNc * 4);
    int*   rowst  = (int*)carve((size_t)(NNc + 1) * 4);
    int*   part   = (int*)carve((size_t)NSB * 4);
    int2*  csr_se = (int2*)carve((size_t)NEc * 8);
    short* we1h   = (short*)carve((size_t)3 * 128 * 384 * 2);
    short* we1l   = (short*)carve((size_t)3 * 128 * 384 * 2);
    short* we2h   = (short*)carve((size_t)3 * 128 * 128 * 2);
    short* we2l   = (short*)carve((size_t)3 * 128 * 128 * 2);
    short* wn1h   = (short*)carve((size_t)3 * 128 * 256 * 2);
    short* wn1l   = (short*)carve((size_t)3 * 128 * 256 * 2);
    short* wn2h   = (short*)carve((size_t)3 * 128 * 128 * 2);
    short* wn2l   = (short*)carve((size_t)3 * 128 * 128 * 2);
    short* wf1h   = (short*)carve((size_t)128 * 384 * 2);
    short* wf1l   = (short*)carve((size_t)128 * 384 * 2);
    short* wf2h   = (short*)carve((size_t)128 * 128 * 2);
    short* wf2l   = (short*)carve((size_t)128 * 128 * 2);

    const int TB = 256;
    const int gN  = (NNc + TB - 1) / TB;
    const int gE  = (NEc + TB - 1) / TB;

    // fragment-linear weight planes (nkc = K/32)
    for (int i = 0; i < 3; i++) {
        k_wconv_frag<<<(8 * 12 * 64 + 255) / 256, TB, 0, stream>>>(We1 + (size_t)i * 384 * 128, we1h + (size_t)i * 128 * 384, we1l + (size_t)i * 128 * 384, 12);
        k_wconv_frag<<<(8 * 4 * 64 + 255) / 256, TB, 0, stream>>>(We2 + (size_t)i * 128 * 128, we2h + (size_t)i * 128 * 128, we2l + (size_t)i * 128 * 128, 4);
        k_wconv_frag<<<(8 * 8 * 64 + 255) / 256, TB, 0, stream>>>(Wn1 + (size_t)i * 256 * 128, wn1h + (size_t)i * 128 * 256, wn1l + (size_t)i * 128 * 256, 8);
        k_wconv_frag<<<(8 * 4 * 64 + 255) / 256, TB, 0, stream>>>(Wn2 + (size_t)i * 128 * 128, wn2h + (size_t)i * 128 * 128, wn2l + (size_t)i * 128 * 128, 4);
    }
    k_wconv_frag<<<(8 * 12 * 64 + 255) / 256, TB, 0, stream>>>(Wf1, wf1h, wf1l, 12);
    k_wconv_frag<<<(8 * 4 * 64 + 255) / 256, TB, 0, stream>>>(Wf2, wf2h, wf2l, 4);

    // CSR build (multi-block scan)
    k_zero_i<<<gN, TB, 0, stream>>>(deg, NNc);
    k_count<<<gE, TB, 0, stream>>>(rcvr, deg);
    k_scan1<<<NSB, TB, 0, stream>>>(deg, part);
    k_scan2<<<1, TB, 0, stream>>>(part);
    k_scan3<<<NSB, TB, 0, stream>>>(deg, part, rowst, cursor);
    k_scatter<<<gE, TB, 0, stream>>>(sndr, rcvr, cursor, csr_se);

    // initial flows
    k_qinit<<<gE, TB, 0, stream>>>(x, r, sndr, rcvr, qh, qt);

    const int gH = (NNc + 63) / 64;
    for (int kit = 0; kit < 4; kit++) {
        k_node_in_f<<<(NNc + 3) / 4, TB, 0, stream>>>(qh, rowst, csr_se, x, Wni, gh_u, gl_u);
        unsigned *zin_h = zAh, *zin_l = zAl, *zout_h = zAh, *zout_l = zAl;
        for (int i = 0; i < 3; i++) {
            zin_h = zout_h; zin_l = zout_l;
            zout_h = (i & 1) ? zAh : zBh;
            zout_l = (i & 1) ? zAl : zBl;
            k_edge_mlp_mfma<<<NEc / 32, 512, 0, stream>>>(
                gh_u, gl_u, zin_h, zin_l, (short*)zout_h, (short*)zout_l,
                we1h + (size_t)i * 128 * 384, we1l + (size_t)i * 128 * 384,
                we2h + (size_t)i * 128 * 128, we2l + (size_t)i * 128 * 128,
                sndr, rcvr, qt, qh, Wei, (i == 0) ? 1 : 0);
            k_node_mlp_mfma<<<NNc / 32, 512, 0, stream>>>(
                gh_u, gl_u, (short*)gh_u, (short*)gl_u, zout_h, zout_l, rowst, csr_se,
                wn1h + (size_t)i * 128 * 256, wn1l + (size_t)i * 128 * 256,
                wn2h + (size_t)i * 128 * 128, wn2l + (size_t)i * 128 * 128);
        }
        k_wf_mfma<<<(4 * E2c) / 32, 512, 0, stream>>>(
            gh_u, gl_u, zout_h, zout_l, wf1h, wf1l, wf2h, wf2l, Wf3, sndr, rcvr,
            r, qh, hl);
        // head propagation: 6 iterations; first reads h_star straight from x (stride 2)
        const float* hin = x; int hstride = 2;
        float* cur = hA;
        for (int jh = 0; jh < 6; jh++) {
            float* dst = (jh == 5) ? ((kit == 3) ? out : hB) : cur;
            k_head_iter<<<gH, 64, 0, stream>>>(x, hin, hstride, hl, rowst, csr_se, dst);
            hin = dst; hstride = 1;
            cur = (dst == hA) ? hB : hA;
        }
        if (kit < 3) k_flows_q<<<gE, TB, 0, stream>>>(hB, r, sndr, rcvr, qt);
    }
}